// Round 1
// baseline (648.306 us; speedup 1.0000x reference)
//
#include <hip/hip_runtime.h>
#include <hip/hip_bf16.h>
#include <cstdint>
#include <cstddef>

typedef __bf16 bf16;
typedef __bf16 bf16x8 __attribute__((ext_vector_type(8)));
typedef float f32x4 __attribute__((ext_vector_type(4)));

#define AS1 __attribute__((address_space(1)))
#define AS3 __attribute__((address_space(3)))

__device__ __forceinline__ void gload_lds16(const void* g, void* l) {
  __builtin_amdgcn_global_load_lds((AS1 void*)g, (AS3 void*)l, 16, 0, 0);
}

// ---------------------------------------------------------------------------
// Transpose + fp32->bf16 convert: out[n][k] = (bf16) in[k][n].  in is [K][N].
// block (32,8), grid (N/32, K/32)
__global__ __launch_bounds__(256)
void transpose_cvt(const float* __restrict__ in, bf16* __restrict__ out,
                   int K, int N) {
  __shared__ float t[32][33];
  const int tx = threadIdx.x, ty = threadIdx.y;
  const int n0 = blockIdx.x * 32, k0 = blockIdx.y * 32;
#pragma unroll
  for (int j = ty; j < 32; j += 8)
    t[j][tx] = in[(size_t)(k0 + j) * N + n0 + tx];
  __syncthreads();
#pragma unroll
  for (int j = ty; j < 32; j += 8)
    out[(size_t)(n0 + j) * K + k0 + tx] = (bf16)t[tx][j];
}

// ---------------------------------------------------------------------------
__global__ __launch_bounds__(256)
void concat_bias(const float* __restrict__ bq, const float* __restrict__ bk,
                 const float* __restrict__ bv, float* __restrict__ o) {
  int i = blockIdx.x * 256 + threadIdx.x;  // grid 12 -> 3072
  if (i < 1024) o[i] = bq[i];
  else if (i < 2048) o[i] = bk[i - 1024];
  else o[i] = bv[i - 2048];
}

// ---------------------------------------------------------------------------
// LayerNorm (torch semantics: ddof=1, eps added to std), fp32 in -> bf16 out.
// One block (256 thr) per row of 1024.
__global__ __launch_bounds__(256)
void ln_kernel(const float* __restrict__ x, bf16* __restrict__ y,
               const float* __restrict__ alpha_p, const float* __restrict__ beta_p) {
  const int row = blockIdx.x;
  const float4 v = ((const float4*)(x + (size_t)row * 1024))[threadIdx.x];
  float s = v.x + v.y + v.z + v.w;
  float ss = v.x * v.x + v.y * v.y + v.z * v.z + v.w * v.w;
#pragma unroll
  for (int m = 1; m < 64; m <<= 1) {
    s += __shfl_xor(s, m);
    ss += __shfl_xor(ss, m);
  }
  __shared__ float red[8];
  const int wave = threadIdx.x >> 6, lane = threadIdx.x & 63;
  if (lane == 0) { red[wave] = s; red[4 + wave] = ss; }
  __syncthreads();
  s = red[0] + red[1] + red[2] + red[3];
  ss = red[4] + red[5] + red[6] + red[7];
  const float mean = s * (1.0f / 1024.0f);
  const float var = fmaxf(ss - 1024.0f * mean * mean, 0.0f) * (1.0f / 1023.0f);
  const float k = alpha_p[0] / (sqrtf(var) + 1e-6f);
  const float beta = beta_p[0];
  union { bf16 b[4]; uint2 u; } pk;
  pk.b[0] = (bf16)((v.x - mean) * k + beta);
  pk.b[1] = (bf16)((v.y - mean) * k + beta);
  pk.b[2] = (bf16)((v.z - mean) * k + beta);
  pk.b[3] = (bf16)((v.w - mean) * k + beta);
  ((uint2*)(y + (size_t)row * 1024))[threadIdx.x] = pk.u;
}

// ---------------------------------------------------------------------------
// GEMM: C[M][N] = A[M][K](bf16) @ Bt[N][K]^T (bf16) + bias[N]
//       optional ReLU, optional fp32 residual add; OutT = bf16 or float.
// 128x128 tile, BK=32, 4 waves (2x2), 4x4 16x16x32 frags per wave.
template <typename OutT, bool RELU, bool RESID>
__global__ __launch_bounds__(256)
void gemm_bt(const bf16* __restrict__ A, const bf16* __restrict__ Bt,
             const float* __restrict__ bias, const float* __restrict__ resid,
             OutT* __restrict__ C, int M, int N, int K) {
  __shared__ bf16 As[128 * 32];
  __shared__ bf16 Bs[128 * 32];
  const int tid = threadIdx.x;
  const int wave = tid >> 6, lane = tid & 63;
  const int l16 = lane & 15, lq = lane >> 4;
  const int bm = blockIdx.x * 128, bn = blockIdx.y * 128;
  const int wr = wave >> 1, wc = wave & 1;
  f32x4 acc[4][4] = {};
  for (int k0 = 0; k0 < K; k0 += 32) {
    __syncthreads();  // previous compute done reading LDS
#pragma unroll
    for (int i = 0; i < 2; i++) {
      const int sb = wave * 128 + i * 64;   // wave-uniform slot base
      const int s = sb + lane;
      const int r = s >> 2, q = s & 3;
      gload_lds16(A + (size_t)(bm + r) * K + k0 + q * 8, &As[sb * 8]);
      gload_lds16(Bt + (size_t)(bn + r) * K + k0 + q * 8, &Bs[sb * 8]);
    }
    __syncthreads();  // vmcnt(0) drained by barrier -> tiles ready
    bf16x8 a[4], b[4];
#pragma unroll
    for (int m = 0; m < 4; m++)
      a[m] = *(const bf16x8*)&As[(wr * 64 + m * 16 + l16) * 32 + lq * 8];
#pragma unroll
    for (int n = 0; n < 4; n++)
      b[n] = *(const bf16x8*)&Bs[(wc * 64 + n * 16 + l16) * 32 + lq * 8];
#pragma unroll
    for (int m = 0; m < 4; m++)
#pragma unroll
      for (int n = 0; n < 4; n++)
        acc[m][n] = __builtin_amdgcn_mfma_f32_16x16x32_bf16(a[m], b[n], acc[m][n], 0, 0, 0);
  }
  // epilogue: C/D layout col = lane&15, row = (lane>>4)*4 + j  [m89-verified]
#pragma unroll
  for (int m = 0; m < 4; m++) {
    const int row0 = bm + wr * 64 + m * 16 + lq * 4;
#pragma unroll
    for (int n = 0; n < 4; n++) {
      const int col = bn + wc * 64 + n * 16 + l16;
      const float bv = bias[col];
#pragma unroll
      for (int j = 0; j < 4; j++) {
        float v = acc[m][n][j] + bv;
        if (RELU) v = fmaxf(v, 0.0f);
        if (RESID) v += resid[(size_t)(row0 + j) * N + col];
        C[(size_t)(row0 + j) * N + col] = (OutT)v;
      }
    }
  }
}

// ---------------------------------------------------------------------------
// Flash attention.  qkv: [8192][3072] bf16 (Q|K|V each 1024 cols, 16 heads x 64).
// Block: one (b,h), 64 q-rows, 4 waves (16 q-rows each).  KV tile = 64.
// grid (32, 64) = (q-tiles, b*16+h)
__global__ __launch_bounds__(256)
void attn_kernel(const bf16* __restrict__ qkv, bf16* __restrict__ out) {
  __shared__ bf16 Qs[64][72];
  __shared__ bf16 Ks[64][72];
  __shared__ bf16 Vts[64][72];  // Vts[d][kv]
  __shared__ bf16 Ps[64][72];
  const int tid = threadIdx.x;
  const int wave = tid >> 6, lane = tid & 63;
  const int l16 = lane & 15, lq = lane >> 4;
  const int bh = blockIdx.y, b = bh >> 4, h = bh & 15;
  const int q0 = blockIdx.x * 64;
  const size_t rowbase = (size_t)b * 2048;
  const bf16* Qg = qkv + (rowbase + q0) * 3072 + h * 64;
  const bf16* Kg = qkv + rowbase * 3072 + 1024 + h * 64;
  const bf16* Vg = qkv + rowbase * 3072 + 2048 + h * 64;

  // stage Q (64 x 64)
#pragma unroll
  for (int i = 0; i < 2; i++) {
    const int c = i * 256 + tid;
    const int r = c >> 3, cc = c & 7;
    *(uint4*)&Qs[r][cc * 8] = *(const uint4*)&Qg[(size_t)r * 3072 + cc * 8];
  }
  __syncthreads();
  const int qw = wave * 16;
  bf16x8 qa0 = *(const bf16x8*)&Qs[qw + l16][lq * 8];
  bf16x8 qa1 = *(const bf16x8*)&Qs[qw + l16][32 + lq * 8];

  float mrow[4] = {-1e30f, -1e30f, -1e30f, -1e30f};
  float lrow[4] = {0.f, 0.f, 0.f, 0.f};
  f32x4 oacc[4] = {};  // 4 d-frags of 16

  for (int kt = 0; kt < 32; ++kt) {
    const int kv0 = kt * 64;
    __syncthreads();  // everyone done reading Ks/Vts of previous tile
    // stage K (64 kv x 64 d)
#pragma unroll
    for (int i = 0; i < 2; i++) {
      const int c = i * 256 + tid;
      const int r = c >> 3, cc = c & 7;
      *(uint4*)&Ks[r][cc * 8] = *(const uint4*)&Kg[(size_t)(kv0 + r) * 3072 + cc * 8];
    }
    // stage V transposed: Vts[d][kv] = V[kv][d]  (staggered writes for banks)
#pragma unroll
    for (int i = 0; i < 2; i++) {
      const int c = i * 256 + tid;
      const int kv = c >> 3, dc = c & 7;
      const uint4 raw = *(const uint4*)&Vg[(size_t)(kv0 + kv) * 3072 + dc * 8];
      const bf16* tp = (const bf16*)&raw;
#pragma unroll
      for (int t = 0; t < 8; t++) {
        const int j = (t + dc) & 7;
        Vts[dc * 8 + j][kv] = tp[j];
      }
    }
    __syncthreads();

    // scores: S^T frag layout D: col(lane&15)=kv-in-frag, row=(lane>>4)*4+r = q
    f32x4 s[4];
#pragma unroll
    for (int n = 0; n < 4; n++) {
      const bf16x8 kb0 = *(const bf16x8*)&Ks[n * 16 + l16][lq * 8];
      const bf16x8 kb1 = *(const bf16x8*)&Ks[n * 16 + l16][32 + lq * 8];
      f32x4 t = {};
      t = __builtin_amdgcn_mfma_f32_16x16x32_bf16(qa0, kb0, t, 0, 0, 0);
      t = __builtin_amdgcn_mfma_f32_16x16x32_bf16(qa1, kb1, t, 0, 0, 0);
      s[n] = t * 0.125f;  // 1/sqrt(64)
    }
    // online softmax, wave-parallel (row lives in 16 lanes sharing lane>>4)
#pragma unroll
    for (int r = 0; r < 4; r++) {
      float sm = fmaxf(fmaxf(s[0][r], s[1][r]), fmaxf(s[2][r], s[3][r]));
      sm = fmaxf(sm, __shfl_xor(sm, 1));
      sm = fmaxf(sm, __shfl_xor(sm, 2));
      sm = fmaxf(sm, __shfl_xor(sm, 4));
      sm = fmaxf(sm, __shfl_xor(sm, 8));
      const float mnew = fmaxf(mrow[r], sm);
      const float scale = __expf(mrow[r] - mnew);
      float psum = 0.f;
#pragma unroll
      for (int n = 0; n < 4; n++) {
        const float p = __expf(s[n][r] - mnew);
        psum += p;
        Ps[qw + lq * 4 + r][n * 16 + l16] = (bf16)p;
      }
      psum += __shfl_xor(psum, 1);
      psum += __shfl_xor(psum, 2);
      psum += __shfl_xor(psum, 4);
      psum += __shfl_xor(psum, 8);
      lrow[r] = lrow[r] * scale + psum;
      mrow[r] = mnew;
#pragma unroll
      for (int nd = 0; nd < 4; nd++) oacc[nd][r] *= scale;
    }
    // PV: A = P strip (16 x 64), B = V (64 kv x 64 d) via Vts
    const bf16x8 pa0 = *(const bf16x8*)&Ps[qw + l16][lq * 8];
    const bf16x8 pa1 = *(const bf16x8*)&Ps[qw + l16][32 + lq * 8];
#pragma unroll
    for (int nd = 0; nd < 4; nd++) {
      const bf16x8 vb0 = *(const bf16x8*)&Vts[nd * 16 + l16][lq * 8];
      const bf16x8 vb1 = *(const bf16x8*)&Vts[nd * 16 + l16][32 + lq * 8];
      oacc[nd] = __builtin_amdgcn_mfma_f32_16x16x32_bf16(pa0, vb0, oacc[nd], 0, 0, 0);
      oacc[nd] = __builtin_amdgcn_mfma_f32_16x16x32_bf16(pa1, vb1, oacc[nd], 0, 0, 0);
    }
  }
  // write O / l
#pragma unroll
  for (int nd = 0; nd < 4; nd++) {
#pragma unroll
    for (int r = 0; r < 4; r++) {
      const int row = q0 + qw + lq * 4 + r;
      out[(rowbase + row) * 1024 + h * 64 + nd * 16 + l16] =
          (bf16)(oacc[nd][r] / lrow[r]);
    }
  }
}

// ---------------------------------------------------------------------------
extern "C" void kernel_launch(void* const* d_in, const int* in_sizes, int n_in,
                              void* d_out, int out_size, void* d_ws, size_t ws_size,
                              hipStream_t stream) {
  const float* x      = (const float*)d_in[0];
  const float* wq     = (const float*)d_in[1];
  const float* bq     = (const float*)d_in[2];
  const float* wk     = (const float*)d_in[3];
  const float* bk     = (const float*)d_in[4];
  const float* wv     = (const float*)d_in[5];
  const float* bv     = (const float*)d_in[6];
  const float* wo     = (const float*)d_in[7];
  const float* bo     = (const float*)d_in[8];
  const float* w1     = (const float*)d_in[9];
  const float* b1     = (const float*)d_in[10];
  const float* w2     = (const float*)d_in[11];
  const float* b2     = (const float*)d_in[12];
  const float* alpha1 = (const float*)d_in[13];
  const float* bias1  = (const float*)d_in[14];
  const float* alpha2 = (const float*)d_in[15];
  const float* bias2  = (const float*)d_in[16];
  float* out = (float*)d_out;  // h lives here, then final output

  const size_t MB = 1024ull * 1024ull;
  char* ws = (char*)d_ws;
  bf16*  wqkvT = (bf16*)(ws);                 // [3072][1024]   6 MB
  bf16*  woT   = (bf16*)(ws + 6 * MB);        // [1024][1024]   2 MB
  bf16*  w1T   = (bf16*)(ws + 8 * MB);        // [4096][1024]   8 MB
  bf16*  w2T   = (bf16*)(ws + 16 * MB);       // [1024][4096]   8 MB
  float* bqkv  = (float*)(ws + 24 * MB);      // [3072]
  bf16*  Z     = (bf16*)(ws + 24 * MB + 65536);        // [8192][1024] 16 MB (z1 then z2)
  bf16*  QKV   = (bf16*)(ws + 40 * MB + 65536);        // [8192][3072] 48 MB (later ffn1 64MB)
  bf16*  AO    = (bf16*)(ws + 88 * MB + 65536);        // [8192][1024] 16 MB
  bf16*  FFN1  = QKV;  // [8192][4096] 64 MB, overlays dead QKV+AO region

  const dim3 tb(32, 8);
  transpose_cvt<<<dim3(32, 32), tb, 0, stream>>>(wq, wqkvT, 1024, 1024);
  transpose_cvt<<<dim3(32, 32), tb, 0, stream>>>(wk, wqkvT + 1024 * 1024, 1024, 1024);
  transpose_cvt<<<dim3(32, 32), tb, 0, stream>>>(wv, wqkvT + 2 * 1024 * 1024, 1024, 1024);
  transpose_cvt<<<dim3(32, 32), tb, 0, stream>>>(wo, woT, 1024, 1024);
  transpose_cvt<<<dim3(128, 32), tb, 0, stream>>>(w1, w1T, 1024, 4096);
  transpose_cvt<<<dim3(32, 128), tb, 0, stream>>>(w2, w2T, 4096, 1024);
  concat_bias<<<12, 256, 0, stream>>>(bq, bk, bv, bqkv);

  // LN1 -> z1
  ln_kernel<<<8192, 256, 0, stream>>>(x, Z, alpha1, bias1);
  // QKV = z1 @ [wq|wk|wv] + [bq|bk|bv]
  gemm_bt<bf16, false, false><<<dim3(64, 24), 256, 0, stream>>>(
      Z, wqkvT, bqkv, nullptr, QKV, 8192, 3072, 1024);
  // attention -> AO
  attn_kernel<<<dim3(32, 64), 256, 0, stream>>>(QKV, AO);
  // h = x + AO @ wo + bo   (h in d_out)
  gemm_bt<float, false, true><<<dim3(64, 8), 256, 0, stream>>>(
      AO, woT, bo, x, out, 8192, 1024, 1024);
  // LN2 -> z2
  ln_kernel<<<8192, 256, 0, stream>>>(out, Z, alpha2, bias2);
  // ffn1 = relu(z2 @ w1 + b1)
  gemm_bt<bf16, true, false><<<dim3(64, 32), 256, 0, stream>>>(
      Z, w1T, b1, nullptr, FFN1, 8192, 4096, 1024);
  // out = h + ffn1 @ w2 + b2   (in-place on d_out)
  gemm_bt<float, false, true><<<dim3(64, 8), 256, 0, stream>>>(
      FFN1, w2T, b2, out, out, 8192, 1024, 4096);
}

// Round 2
// 459.012 us; speedup vs baseline: 1.4124x; 1.4124x over previous
//
#include <hip/hip_runtime.h>
#include <hip/hip_bf16.h>
#include <cstdint>
#include <cstddef>

typedef __bf16 bf16;
typedef __bf16 bf16x4 __attribute__((ext_vector_type(4)));
typedef __bf16 bf16x8 __attribute__((ext_vector_type(8)));
typedef float f32x4 __attribute__((ext_vector_type(4)));

#define AS1 __attribute__((address_space(1)))
#define AS3 __attribute__((address_space(3)))

__device__ __forceinline__ void gload_lds16(const void* g, void* l) {
  __builtin_amdgcn_global_load_lds((AS1 void*)g, (AS3 void*)l, 16, 0, 0);
}

// ---------------------------------------------------------------------------
// Transpose + fp32->bf16 convert: out[n][k] = (bf16) in[k][n].  in is [K][N].
__global__ __launch_bounds__(256)
void transpose_cvt(const float* __restrict__ in, bf16* __restrict__ out,
                   int K, int N) {
  __shared__ float t[32][33];
  const int tx = threadIdx.x, ty = threadIdx.y;
  const int n0 = blockIdx.x * 32, k0 = blockIdx.y * 32;
#pragma unroll
  for (int j = ty; j < 32; j += 8)
    t[j][tx] = in[(size_t)(k0 + j) * N + n0 + tx];
  __syncthreads();
#pragma unroll
  for (int j = ty; j < 32; j += 8)
    out[(size_t)(n0 + j) * K + k0 + tx] = (bf16)t[tx][j];
}

// ---------------------------------------------------------------------------
__global__ __launch_bounds__(256)
void concat_bias(const float* __restrict__ bq, const float* __restrict__ bk,
                 const float* __restrict__ bv, float* __restrict__ o) {
  int i = blockIdx.x * 256 + threadIdx.x;
  if (i < 1024) o[i] = bq[i];
  else if (i < 2048) o[i] = bk[i - 1024];
  else o[i] = bv[i - 2048];
}

// ---------------------------------------------------------------------------
// LayerNorm (torch semantics: ddof=1, eps on std), fp32 in -> bf16 out.
__global__ __launch_bounds__(256)
void ln_kernel(const float* __restrict__ x, bf16* __restrict__ y,
               const float* __restrict__ alpha_p, const float* __restrict__ beta_p) {
  const int row = blockIdx.x;
  const float4 v = ((const float4*)(x + (size_t)row * 1024))[threadIdx.x];
  float s = v.x + v.y + v.z + v.w;
  float ss = v.x * v.x + v.y * v.y + v.z * v.z + v.w * v.w;
#pragma unroll
  for (int m = 1; m < 64; m <<= 1) {
    s += __shfl_xor(s, m);
    ss += __shfl_xor(ss, m);
  }
  __shared__ float red[8];
  const int wave = threadIdx.x >> 6, lane = threadIdx.x & 63;
  if (lane == 0) { red[wave] = s; red[4 + wave] = ss; }
  __syncthreads();
  s = red[0] + red[1] + red[2] + red[3];
  ss = red[4] + red[5] + red[6] + red[7];
  const float mean = s * (1.0f / 1024.0f);
  const float var = fmaxf(ss - 1024.0f * mean * mean, 0.0f) * (1.0f / 1023.0f);
  const float k = alpha_p[0] / (sqrtf(var) + 1e-6f);
  const float beta = beta_p[0];
  union { bf16 b[4]; uint2 u; } pk;
  pk.b[0] = (bf16)((v.x - mean) * k + beta);
  pk.b[1] = (bf16)((v.y - mean) * k + beta);
  pk.b[2] = (bf16)((v.z - mean) * k + beta);
  pk.b[3] = (bf16)((v.w - mean) * k + beta);
  ((uint2*)(y + (size_t)row * 1024))[threadIdx.x] = pk.u;
}

// ---------------------------------------------------------------------------
// GEMM: C[M][N] = A[M][K](bf16) @ Bt[N][K]^T (bf16) + bias[N], 128x128 tile.
template <typename OutT, bool RELU, bool RESID>
__global__ __launch_bounds__(256)
void gemm_bt(const bf16* __restrict__ A, const bf16* __restrict__ Bt,
             const float* __restrict__ bias, const float* __restrict__ resid,
             OutT* __restrict__ C, int M, int N, int K) {
  __shared__ bf16 As[128 * 32];
  __shared__ bf16 Bs[128 * 32];
  const int tid = threadIdx.x;
  const int wave = tid >> 6, lane = tid & 63;
  const int l16 = lane & 15, lq = lane >> 4;
  // XCD-aware swizzle (T1): contiguous work chunk per XCD. nwg % 8 == 0 here.
  const int nwg = gridDim.x * gridDim.y;
  const int id = blockIdx.y * gridDim.x + blockIdx.x;
  const int w = (id & 7) * (nwg >> 3) + (id >> 3);
  const int bm = (w % gridDim.x) * 128, bn = (w / gridDim.x) * 128;
  const int wr = wave >> 1, wc = wave & 1;
  f32x4 acc[4][4] = {};
  for (int k0 = 0; k0 < K; k0 += 32) {
    __syncthreads();
#pragma unroll
    for (int i = 0; i < 2; i++) {
      const int sb = wave * 128 + i * 64;
      const int s = sb + lane;
      const int r = s >> 2, q = s & 3;
      gload_lds16(A + (size_t)(bm + r) * K + k0 + q * 8, &As[sb * 8]);
      gload_lds16(Bt + (size_t)(bn + r) * K + k0 + q * 8, &Bs[sb * 8]);
    }
    __syncthreads();
    bf16x8 a[4], b[4];
#pragma unroll
    for (int m = 0; m < 4; m++)
      a[m] = *(const bf16x8*)&As[(wr * 64 + m * 16 + l16) * 32 + lq * 8];
#pragma unroll
    for (int n = 0; n < 4; n++)
      b[n] = *(const bf16x8*)&Bs[(wc * 64 + n * 16 + l16) * 32 + lq * 8];
#pragma unroll
    for (int m = 0; m < 4; m++)
#pragma unroll
      for (int n = 0; n < 4; n++)
        acc[m][n] = __builtin_amdgcn_mfma_f32_16x16x32_bf16(a[m], b[n], acc[m][n], 0, 0, 0);
  }
#pragma unroll
  for (int m = 0; m < 4; m++) {
    const int row0 = bm + wr * 64 + m * 16 + lq * 4;
#pragma unroll
    for (int n = 0; n < 4; n++) {
      const int col = bn + wc * 64 + n * 16 + l16;
      const float bv = bias[col];
#pragma unroll
      for (int j = 0; j < 4; j++) {
        float v = acc[m][n][j] + bv;
        if (RELU) v = fmaxf(v, 0.0f);
        if (RESID) v += resid[(size_t)(row0 + j) * N + col];
        C[(size_t)(row0 + j) * N + col] = (OutT)v;
      }
    }
  }
}

// ---------------------------------------------------------------------------
// V^T prep: Vt[bh*64 + d][s] = V[s][d] from QKV (V cols 2048 + h*64).
// grid (32 sblk, 64 bh), 256 threads.
__global__ __launch_bounds__(256)
void vt_prep(const bf16* __restrict__ qkv, bf16* __restrict__ Vt) {
  __shared__ __align__(16) bf16 Vl[64 * 64];
  const int tid = threadIdx.x;
  const int sblk = blockIdx.x, bh = blockIdx.y, b = bh >> 4, h = bh & 15;
  const size_t srow = (size_t)b * 2048 + sblk * 64;
  const bf16* src = qkv + srow * 3072 + 2048 + h * 64;
  // phase1: stage rows, swizzled col' = dseg ^ (s&7) ^ (s>>3)
#pragma unroll
  for (int i = 0; i < 2; i++) {
    int c = i * 256 + tid;
    int s = c >> 3, dseg = c & 7;
    int col = dseg ^ (s & 7) ^ (s >> 3);
    *(uint4*)((char*)Vl + s * 128 + col * 16) =
        *(const uint4*)(src + (size_t)s * 3072 + dseg * 8);
  }
  __syncthreads();
  // phase2: write rows d, coalesced 16B chunks (8-lane groups contiguous)
  bf16* dst = Vt + (size_t)bh * 64 * 2048 + sblk * 64;
#pragma unroll
  for (int i = 0; i < 2; i++) {
    int c = i * 256 + tid;
    int d = c >> 3, grp = c & 7;
    union { bf16 v[8]; uint4 u; } pk;
#pragma unroll
    for (int j = 0; j < 8; j++) {
      int s = grp * 8 + j;
      int col = (d >> 3) ^ (s & 7) ^ (s >> 3);
      pk.v[j] = *(const bf16*)((char*)Vl + s * 128 + col * 16 + ((2 * d) & 15));
    }
    *(uint4*)(dst + (size_t)d * 2048 + grp * 8) = pk.u;
  }
}

// ---------------------------------------------------------------------------
// Flash attention v2.  Swapped QK^T (lane-local P rows), fixed-max softmax,
// L via ones-MFMA, V^T staged from global Vt, all LDS reads XOR-swizzled,
// double-buffered K/V with counted vmcnt pipeline.
// Block: 256 thr (4 waves), 256 q-rows (64/wave), KV tile 64.  grid (8, 64).
__global__ __launch_bounds__(256, 2)
void attn_kernel(const bf16* __restrict__ qkv, const bf16* __restrict__ Vt,
                 bf16* __restrict__ out) {
  __shared__ __align__(16) bf16 smem[32768];  // 64 KB
  bf16* Qs = smem;             // [256][64] linear, swizzled contents
  bf16* Ks = smem + 16384;     // 2 x [64][64]
  bf16* Vs = smem + 24576;     // 2 x [64][64]  (rows = d, cols = kv)
  const int tid = threadIdx.x, wave = tid >> 6, lane = tid & 63;
  const int l16 = lane & 15, lq = lane >> 4;
  // XCD swizzle: contiguous bh chunk per XCD (512 blocks, 64/XCD)
  const int id = blockIdx.y * 8 + blockIdx.x;
  const int w = (id & 7) * 64 + (id >> 3);
  const int qblk = w & 7, bh = w >> 3;
  const int b = bh >> 4, h = bh & 15;
  const int q0 = qblk * 256;
  const size_t rowbase = (size_t)b * 2048;
  const bf16* Qg = qkv + (rowbase + q0) * 3072 + h * 64;
  const bf16* Kg = qkv + rowbase * 3072 + 1024 + h * 64;
  const bf16* Vg = Vt + (size_t)bh * 64 * 2048;

  // ---- prologue: stage Q (pre-swizzled source -> linear LDS) ----
#pragma unroll
  for (int i = 0; i < 8; i++) {
    const int c = i * 256 + wave * 64;   // wave-uniform chunk base
    const int cl = c + lane;
    const int r = cl >> 3, seg = cl & 7;
    gload_lds16(Qg + (size_t)r * 3072 + (seg ^ (r & 7)) * 8, (char*)Qs + c * 16);
  }
  // stage K/V tile kt into buffer buf
  auto stageKV = [&](int kt, int buf) {
    const int kv0 = kt * 64;
#pragma unroll
    for (int i = 0; i < 2; i++) {
      const int c = i * 256 + wave * 64;
      const int cl = c + lane;
      const int r = cl >> 3, seg = cl & 7;
      gload_lds16(Kg + (size_t)(kv0 + r) * 3072 + (seg ^ (r & 7)) * 8,
                  (char*)Ks + buf * 8192 + c * 16);
      gload_lds16(Vg + (size_t)r * 2048 + kv0 + (seg ^ (r & 7)) * 8,
                  (char*)Vs + buf * 8192 + c * 16);
    }
  };
  stageKV(0, 0);

  f32x4 oacc[4][4] = {};
  f32x4 lacc[4] = {};
  bf16x8 qb[4][2];
  bf16x8 onesb;
#pragma unroll
  for (int j = 0; j < 8; j++) onesb[j] = (bf16)1.0f;

  for (int t = 0; t < 32; t++) {
    const int cur = t & 1;
    __builtin_amdgcn_s_barrier();          // everyone done reading buf cur^1
    if (t < 31) stageKV(t + 1, cur ^ 1);   // prefetch next tile
    if (t < 31) asm volatile("s_waitcnt vmcnt(4)" ::: "memory");
    else        asm volatile("s_waitcnt vmcnt(0)" ::: "memory");
    __builtin_amdgcn_s_barrier();          // tile t visible to all waves
    const char* Kb = (const char*)Ks + cur * 8192;
    const char* Vb = (const char*)Vs + cur * 8192;

    if (t == 0) {  // load Q fragments (B-operand: row q = wave*64+g*16+l16)
#pragma unroll
      for (int g = 0; g < 4; g++)
#pragma unroll
        for (int H = 0; H < 2; H++) {
          const int row = wave * 64 + g * 16 + l16;
          const int col = (H * 64 + lq * 16) ^ ((row & 7) << 4);
          qb[g][H] = *(const bf16x8*)((const char*)Qs + row * 128 + col);
        }
    }
    // K A-fragments: row kv = m*16+l16, k-slice d = H*32+lq*8
    bf16x8 ka[2][4];
#pragma unroll
    for (int H = 0; H < 2; H++)
#pragma unroll
      for (int m = 0; m < 4; m++) {
        const int row = m * 16 + l16;
        const int col = (H * 64 + lq * 16) ^ ((row & 7) << 4);
        ka[H][m] = *(const bf16x8*)(Kb + row * 128 + col);
      }
    // V B-fragments: row d = nd*16+l16; k'->kv map gives two contiguous b64s
    bf16x8 vb[2][4];
#pragma unroll
    for (int H = 0; H < 2; H++)
#pragma unroll
      for (int nd = 0; nd < 4; nd++) {
        const int row = nd * 16 + l16;
        const int xorv = (row & 7) << 4;
        const int c1 = (H * 64 + lq * 8) ^ xorv;
        const int c2 = (H * 64 + lq * 8 + 32) ^ xorv;
        bf16x4 lo = *(const bf16x4*)(Vb + row * 128 + c1);
        bf16x4 hi = *(const bf16x4*)(Vb + row * 128 + c2);
        vb[H][nd] = __builtin_shufflevector(lo, hi, 0, 1, 2, 3, 4, 5, 6, 7);
      }
    // per q-group: S^T = K·Q^T (col = q = l16), p = exp2(s*log2e/8), PV + L
#pragma unroll
    for (int g = 0; g < 4; g++) {
      f32x4 sc[4];
#pragma unroll
      for (int m = 0; m < 4; m++) {
        f32x4 z = {};
        sc[m] = __builtin_amdgcn_mfma_f32_16x16x32_bf16(ka[0][m], qb[g][0], z, 0, 0, 0);
        sc[m] = __builtin_amdgcn_mfma_f32_16x16x32_bf16(ka[1][m], qb[g][1], sc[m], 0, 0, 0);
      }
      bf16x8 pa0, pa1;
#pragma unroll
      for (int m = 0; m < 2; m++)
#pragma unroll
        for (int r = 0; r < 4; r++)
          pa0[m * 4 + r] = (bf16)__builtin_amdgcn_exp2f(sc[m][r] * 0.1803368801f);
#pragma unroll
      for (int m = 0; m < 2; m++)
#pragma unroll
        for (int r = 0; r < 4; r++)
          pa1[m * 4 + r] = (bf16)__builtin_amdgcn_exp2f(sc[2 + m][r] * 0.1803368801f);
#pragma unroll
      for (int nd = 0; nd < 4; nd++) {
        oacc[g][nd] = __builtin_amdgcn_mfma_f32_16x16x32_bf16(pa0, vb[0][nd], oacc[g][nd], 0, 0, 0);
        oacc[g][nd] = __builtin_amdgcn_mfma_f32_16x16x32_bf16(pa1, vb[1][nd], oacc[g][nd], 0, 0, 0);
      }
      lacc[g] = __builtin_amdgcn_mfma_f32_16x16x32_bf16(pa0, onesb, lacc[g], 0, 0, 0);
      lacc[g] = __builtin_amdgcn_mfma_f32_16x16x32_bf16(pa1, onesb, lacc[g], 0, 0, 0);
    }
  }
  // output: rows q = wave*64+g*16+lq*4+r, col d = nd*16+l16; L in matching layout
#pragma unroll
  for (int g = 0; g < 4; g++) {
#pragma unroll
    for (int r = 0; r < 4; r++) {
      const float inv = 1.0f / lacc[g][r];
      const size_t row = rowbase + q0 + wave * 64 + g * 16 + lq * 4 + r;
#pragma unroll
      for (int nd = 0; nd < 4; nd++)
        out[row * 1024 + h * 64 + nd * 16 + l16] = (bf16)(oacc[g][nd][r] * inv);
    }
  }
}

// ---------------------------------------------------------------------------
extern "C" void kernel_launch(void* const* d_in, const int* in_sizes, int n_in,
                              void* d_out, int out_size, void* d_ws, size_t ws_size,
                              hipStream_t stream) {
  const float* x      = (const float*)d_in[0];
  const float* wq     = (const float*)d_in[1];
  const float* bq     = (const float*)d_in[2];
  const float* wk     = (const float*)d_in[3];
  const float* bk     = (const float*)d_in[4];
  const float* wv     = (const float*)d_in[5];
  const float* bv     = (const float*)d_in[6];
  const float* wo     = (const float*)d_in[7];
  const float* bo     = (const float*)d_in[8];
  const float* w1     = (const float*)d_in[9];
  const float* b1     = (const float*)d_in[10];
  const float* w2     = (const float*)d_in[11];
  const float* b2     = (const float*)d_in[12];
  const float* alpha1 = (const float*)d_in[13];
  const float* bias1  = (const float*)d_in[14];
  const float* alpha2 = (const float*)d_in[15];
  const float* bias2  = (const float*)d_in[16];
  float* out = (float*)d_out;  // h lives here, then final output

  const size_t MB = 1024ull * 1024ull;
  char* ws = (char*)d_ws;
  bf16*  wqkvT = (bf16*)(ws);                 // [3072][1024]   6 MB
  bf16*  woT   = (bf16*)(ws + 6 * MB);        // [1024][1024]   2 MB
  bf16*  w1T   = (bf16*)(ws + 8 * MB);        // [4096][1024]   8 MB
  bf16*  w2T   = (bf16*)(ws + 16 * MB);       // [1024][4096]   8 MB
  float* bqkv  = (float*)(ws + 24 * MB);      // [3072]
  bf16*  Z     = (bf16*)(ws + 24 * MB + 65536);   // [8192][1024] 16 MB (z1, Vt, z2)
  bf16*  Vtb   = Z;                                // Vt overlays dead z1
  bf16*  QKV   = (bf16*)(ws + 40 * MB + 65536);   // [8192][3072] 48 MB
  bf16*  AO    = (bf16*)(ws + 88 * MB + 65536);   // [8192][1024] 16 MB
  bf16*  FFN1  = QKV;  // [8192][4096] 64 MB, overlays dead QKV+AO region

  const dim3 tb(32, 8);
  transpose_cvt<<<dim3(32, 32), tb, 0, stream>>>(wq, wqkvT, 1024, 1024);
  transpose_cvt<<<dim3(32, 32), tb, 0, stream>>>(wk, wqkvT + 1024 * 1024, 1024, 1024);
  transpose_cvt<<<dim3(32, 32), tb, 0, stream>>>(wv, wqkvT + 2 * 1024 * 1024, 1024, 1024);
  transpose_cvt<<<dim3(32, 32), tb, 0, stream>>>(wo, woT, 1024, 1024);
  transpose_cvt<<<dim3(128, 32), tb, 0, stream>>>(w1, w1T, 1024, 4096);
  transpose_cvt<<<dim3(32, 128), tb, 0, stream>>>(w2, w2T, 4096, 1024);
  concat_bias<<<12, 256, 0, stream>>>(bq, bk, bv, bqkv);

  // LN1 -> z1
  ln_kernel<<<8192, 256, 0, stream>>>(x, Z, alpha1, bias1);
  // QKV = z1 @ [wq|wk|wv] + [bq|bk|bv]
  gemm_bt<bf16, false, false><<<dim3(64, 24), 256, 0, stream>>>(
      Z, wqkvT, bqkv, nullptr, QKV, 8192, 3072, 1024);
  // V^T (overlays dead z1)
  vt_prep<<<dim3(32, 64), 256, 0, stream>>>(QKV, Vtb);
  // attention -> AO
  attn_kernel<<<dim3(8, 64), 256, 0, stream>>>(QKV, Vtb, AO);
  // h = x + AO @ wo + bo   (h in d_out)
  gemm_bt<float, false, true><<<dim3(64, 8), 256, 0, stream>>>(
      AO, woT, bo, x, out, 8192, 1024, 1024);
  // LN2 -> z2
  ln_kernel<<<8192, 256, 0, stream>>>(out, Z, alpha2, bias2);
  // ffn1 = relu(z2 @ w1 + b1)
  gemm_bt<bf16, true, false><<<dim3(64, 32), 256, 0, stream>>>(
      Z, w1T, b1, nullptr, FFN1, 8192, 4096, 1024);
  // out = h + ffn1 @ w2 + b2   (in-place on d_out)
  gemm_bt<float, false, true><<<dim3(64, 8), 256, 0, stream>>>(
      FFN1, w2T, b2, out, out, 8192, 1024, 4096);
}

// Round 3
// 381.435 us; speedup vs baseline: 1.6997x; 1.2034x over previous
//
#include <hip/hip_runtime.h>
#include <hip/hip_bf16.h>
#include <cstdint>
#include <cstddef>

typedef __bf16 bf16;
typedef __bf16 bf16x4 __attribute__((ext_vector_type(4)));
typedef __bf16 bf16x8 __attribute__((ext_vector_type(8)));
typedef float f32x4 __attribute__((ext_vector_type(4)));

#define AS1 __attribute__((address_space(1)))
#define AS3 __attribute__((address_space(3)))

__device__ __forceinline__ void gload_lds16(const void* g, void* l) {
  __builtin_amdgcn_global_load_lds((AS1 void*)g, (AS3 void*)l, 16, 0, 0);
}

// ---------------------------------------------------------------------------
// Transpose + fp32->bf16 convert: out[n][k] = (bf16) in[k][n].  in is [K][N].
__global__ __launch_bounds__(256)
void transpose_cvt(const float* __restrict__ in, bf16* __restrict__ out,
                   int K, int N) {
  __shared__ float t[32][33];
  const int tx = threadIdx.x, ty = threadIdx.y;
  const int n0 = blockIdx.x * 32, k0 = blockIdx.y * 32;
#pragma unroll
  for (int j = ty; j < 32; j += 8)
    t[j][tx] = in[(size_t)(k0 + j) * N + n0 + tx];
  __syncthreads();
#pragma unroll
  for (int j = ty; j < 32; j += 8)
    out[(size_t)(n0 + j) * K + k0 + tx] = (bf16)t[tx][j];
}

// ---------------------------------------------------------------------------
__global__ __launch_bounds__(256)
void concat_bias(const float* __restrict__ bq, const float* __restrict__ bk,
                 const float* __restrict__ bv, float* __restrict__ o) {
  int i = blockIdx.x * 256 + threadIdx.x;
  if (i < 1024) o[i] = bq[i];
  else if (i < 2048) o[i] = bk[i - 1024];
  else o[i] = bv[i - 2048];
}

// ---------------------------------------------------------------------------
// LayerNorm (torch semantics: ddof=1, eps on std), fp32 in -> bf16 out.
__global__ __launch_bounds__(256)
void ln_kernel(const float* __restrict__ x, bf16* __restrict__ y,
               const float* __restrict__ alpha_p, const float* __restrict__ beta_p) {
  const int row = blockIdx.x;
  const float4 v = ((const float4*)(x + (size_t)row * 1024))[threadIdx.x];
  float s = v.x + v.y + v.z + v.w;
  float ss = v.x * v.x + v.y * v.y + v.z * v.z + v.w * v.w;
#pragma unroll
  for (int m = 1; m < 64; m <<= 1) {
    s += __shfl_xor(s, m);
    ss += __shfl_xor(ss, m);
  }
  __shared__ float red[8];
  const int wave = threadIdx.x >> 6, lane = threadIdx.x & 63;
  if (lane == 0) { red[wave] = s; red[4 + wave] = ss; }
  __syncthreads();
  s = red[0] + red[1] + red[2] + red[3];
  ss = red[4] + red[5] + red[6] + red[7];
  const float mean = s * (1.0f / 1024.0f);
  const float var = fmaxf(ss - 1024.0f * mean * mean, 0.0f) * (1.0f / 1023.0f);
  const float k = alpha_p[0] / (sqrtf(var) + 1e-6f);
  const float beta = beta_p[0];
  union { bf16 b[4]; uint2 u; } pk;
  pk.b[0] = (bf16)((v.x - mean) * k + beta);
  pk.b[1] = (bf16)((v.y - mean) * k + beta);
  pk.b[2] = (bf16)((v.z - mean) * k + beta);
  pk.b[3] = (bf16)((v.w - mean) * k + beta);
  ((uint2*)(y + (size_t)row * 1024))[threadIdx.x] = pk.u;
}

// ---------------------------------------------------------------------------
// GEMM: C[M][N] = A[M][K](bf16) @ Bt[N][K]^T (bf16) + bias[N], 128x128 tile.
// Min-2-phase double-buffered pipeline (stage t+1 issued before compute t,
// single vmcnt-drain+barrier per K-tile), XOR-swizzled LDS (both sides),
// bm-major XCD swizzle (2MB A-slice per XCD -> L2-resident).
template <typename OutT, bool RELU, bool RESID>
__global__ __launch_bounds__(256)
void gemm_bt(const bf16* __restrict__ A, const bf16* __restrict__ Bt,
             const float* __restrict__ bias, const float* __restrict__ resid,
             OutT* __restrict__ C, int M, int N, int K) {
  __shared__ __align__(16) bf16 As[2][128 * 32];
  __shared__ __align__(16) bf16 Bs[2][128 * 32];
  const int tid = threadIdx.x;
  const int wave = tid >> 6, lane = tid & 63;
  const int l16 = lane & 15, lq = lane >> 4;
  // XCD swizzle: contiguous chunk per XCD, bn fastest within chunk.
  const int nwg = gridDim.x * gridDim.y;
  const int id = blockIdx.y * gridDim.x + blockIdx.x;
  const int w = (id & 7) * (nwg >> 3) + (id >> 3);
  const int bm = (w / gridDim.y) * 128, bn = (w % gridDim.y) * 128;
  const int wr = wave >> 1, wc = wave & 1;

  // per-lane unswizzled (row-in-chunk, seg) for linear-dest staging (rule #21)
  const int tmp = (lane * 16) ^ (((lane >> 3) & 7) << 4);
  const int srow = tmp >> 6, sseg = (tmp >> 4) & 3;
  const bf16* Ab = A + (size_t)bm * K + sseg * 8;
  const bf16* Bb = Bt + (size_t)bn * K + sseg * 8;

  auto STAGE = [&](int k0, int buf) {
#pragma unroll
    for (int i = 0; i < 2; i++) {
      const int chunk = wave * 2 + i;  // wave-uniform LDS base, [0,8)
      const int r = chunk * 16 + srow;
      gload_lds16(Ab + (size_t)r * K + k0, (char*)As[buf] + chunk * 1024);
      gload_lds16(Bb + (size_t)r * K + k0, (char*)Bs[buf] + chunk * 1024);
    }
  };
  // swizzled byte offset for logical (row, 16B-slot lq): XOR slot3 with rowpair
  auto swz = [&](int row) -> int {
    return (row >> 1) * 128 + (((((row & 1) << 2) | lq) ^ ((row >> 1) & 7)) << 4);
  };

  STAGE(0, 0);
  __syncthreads();  // compiler drains vmcnt(0) before barrier

  f32x4 acc[4][4] = {};
  const int nk = K >> 5;
  for (int t = 0; t < nk; t++) {
    const int cur = t & 1;
    if (t + 1 < nk) STAGE((t + 1) << 5, cur ^ 1);  // issue-early prefetch
    bf16x8 a[4], b[4];
#pragma unroll
    for (int m = 0; m < 4; m++)
      a[m] = *(const bf16x8*)((const char*)As[cur] + swz(wr * 64 + m * 16 + l16));
#pragma unroll
    for (int n = 0; n < 4; n++)
      b[n] = *(const bf16x8*)((const char*)Bs[cur] + swz(wc * 64 + n * 16 + l16));
#pragma unroll
    for (int m = 0; m < 4; m++)
#pragma unroll
      for (int n = 0; n < 4; n++)
        acc[m][n] = __builtin_amdgcn_mfma_f32_16x16x32_bf16(a[m], b[n], acc[m][n], 0, 0, 0);
    __syncthreads();  // drains prefetch vmcnt + releases buf[cur] for overwrite
  }
  // epilogue: C/D layout col = lane&15, row = (lane>>4)*4 + j
#pragma unroll
  for (int m = 0; m < 4; m++) {
    const int row0 = bm + wr * 64 + m * 16 + lq * 4;
#pragma unroll
    for (int n = 0; n < 4; n++) {
      const int col = bn + wc * 64 + n * 16 + l16;
      const float bv = bias[col];
#pragma unroll
      for (int j = 0; j < 4; j++) {
        float v = acc[m][n][j] + bv;
        if (RELU) v = fmaxf(v, 0.0f);
        if (RESID) v += resid[(size_t)(row0 + j) * N + col];
        C[(size_t)(row0 + j) * N + col] = (OutT)v;
      }
    }
  }
}

// ---------------------------------------------------------------------------
// V^T prep: Vt[bh*64 + d][s] = V[s][d] from QKV (V cols 2048 + h*64).
__global__ __launch_bounds__(256)
void vt_prep(const bf16* __restrict__ qkv, bf16* __restrict__ Vt) {
  __shared__ __align__(16) bf16 Vl[64 * 64];
  const int tid = threadIdx.x;
  const int sblk = blockIdx.x, bh = blockIdx.y, b = bh >> 4, h = bh & 15;
  const size_t srow = (size_t)b * 2048 + sblk * 64;
  const bf16* src = qkv + srow * 3072 + 2048 + h * 64;
#pragma unroll
  for (int i = 0; i < 2; i++) {
    int c = i * 256 + tid;
    int s = c >> 3, dseg = c & 7;
    int col = dseg ^ (s & 7) ^ (s >> 3);
    *(uint4*)((char*)Vl + s * 128 + col * 16) =
        *(const uint4*)(src + (size_t)s * 3072 + dseg * 8);
  }
  __syncthreads();
  bf16* dst = Vt + (size_t)bh * 64 * 2048 + sblk * 64;
#pragma unroll
  for (int i = 0; i < 2; i++) {
    int c = i * 256 + tid;
    int d = c >> 3, grp = c & 7;
    union { bf16 v[8]; uint4 u; } pk;
#pragma unroll
    for (int j = 0; j < 8; j++) {
      int s = grp * 8 + j;
      int col = (d >> 3) ^ (s & 7) ^ (s >> 3);
      pk.v[j] = *(const bf16*)((char*)Vl + s * 128 + col * 16 + ((2 * d) & 15));
    }
    *(uint4*)(dst + (size_t)d * 2048 + grp * 8) = pk.u;
  }
}

// ---------------------------------------------------------------------------
// Flash attention v2 (unchanged from round 2).
__global__ __launch_bounds__(256, 2)
void attn_kernel(const bf16* __restrict__ qkv, const bf16* __restrict__ Vt,
                 bf16* __restrict__ out) {
  __shared__ __align__(16) bf16 smem[32768];  // 64 KB
  bf16* Qs = smem;             // [256][64] linear, swizzled contents
  bf16* Ks = smem + 16384;     // 2 x [64][64]
  bf16* Vs = smem + 24576;     // 2 x [64][64]  (rows = d, cols = kv)
  const int tid = threadIdx.x, wave = tid >> 6, lane = tid & 63;
  const int l16 = lane & 15, lq = lane >> 4;
  const int id = blockIdx.y * 8 + blockIdx.x;
  const int w = (id & 7) * 64 + (id >> 3);
  const int qblk = w & 7, bh = w >> 3;
  const int b = bh >> 4, h = bh & 15;
  const int q0 = qblk * 256;
  const size_t rowbase = (size_t)b * 2048;
  const bf16* Qg = qkv + (rowbase + q0) * 3072 + h * 64;
  const bf16* Kg = qkv + rowbase * 3072 + 1024 + h * 64;
  const bf16* Vg = Vt + (size_t)bh * 64 * 2048;

#pragma unroll
  for (int i = 0; i < 8; i++) {
    const int c = i * 256 + wave * 64;
    const int cl = c + lane;
    const int r = cl >> 3, seg = cl & 7;
    gload_lds16(Qg + (size_t)r * 3072 + (seg ^ (r & 7)) * 8, (char*)Qs + c * 16);
  }
  auto stageKV = [&](int kt, int buf) {
    const int kv0 = kt * 64;
#pragma unroll
    for (int i = 0; i < 2; i++) {
      const int c = i * 256 + wave * 64;
      const int cl = c + lane;
      const int r = cl >> 3, seg = cl & 7;
      gload_lds16(Kg + (size_t)(kv0 + r) * 3072 + (seg ^ (r & 7)) * 8,
                  (char*)Ks + buf * 8192 + c * 16);
      gload_lds16(Vg + (size_t)r * 2048 + kv0 + (seg ^ (r & 7)) * 8,
                  (char*)Vs + buf * 8192 + c * 16);
    }
  };
  stageKV(0, 0);

  f32x4 oacc[4][4] = {};
  f32x4 lacc[4] = {};
  bf16x8 qb[4][2];
  bf16x8 onesb;
#pragma unroll
  for (int j = 0; j < 8; j++) onesb[j] = (bf16)1.0f;

  for (int t = 0; t < 32; t++) {
    const int cur = t & 1;
    __builtin_amdgcn_s_barrier();
    if (t < 31) stageKV(t + 1, cur ^ 1);
    if (t < 31) asm volatile("s_waitcnt vmcnt(4)" ::: "memory");
    else        asm volatile("s_waitcnt vmcnt(0)" ::: "memory");
    __builtin_amdgcn_s_barrier();
    const char* Kb = (const char*)Ks + cur * 8192;
    const char* Vb = (const char*)Vs + cur * 8192;

    if (t == 0) {
#pragma unroll
      for (int g = 0; g < 4; g++)
#pragma unroll
        for (int H = 0; H < 2; H++) {
          const int row = wave * 64 + g * 16 + l16;
          const int col = (H * 64 + lq * 16) ^ ((row & 7) << 4);
          qb[g][H] = *(const bf16x8*)((const char*)Qs + row * 128 + col);
        }
    }
    bf16x8 ka[2][4];
#pragma unroll
    for (int H = 0; H < 2; H++)
#pragma unroll
      for (int m = 0; m < 4; m++) {
        const int row = m * 16 + l16;
        const int col = (H * 64 + lq * 16) ^ ((row & 7) << 4);
        ka[H][m] = *(const bf16x8*)(Kb + row * 128 + col);
      }
    bf16x8 vb[2][4];
#pragma unroll
    for (int H = 0; H < 2; H++)
#pragma unroll
      for (int nd = 0; nd < 4; nd++) {
        const int row = nd * 16 + l16;
        const int xorv = (row & 7) << 4;
        const int c1 = (H * 64 + lq * 8) ^ xorv;
        const int c2 = (H * 64 + lq * 8 + 32) ^ xorv;
        bf16x4 lo = *(const bf16x4*)(Vb + row * 128 + c1);
        bf16x4 hi = *(const bf16x4*)(Vb + row * 128 + c2);
        vb[H][nd] = __builtin_shufflevector(lo, hi, 0, 1, 2, 3, 4, 5, 6, 7);
      }
#pragma unroll
    for (int g = 0; g < 4; g++) {
      f32x4 sc[4];
#pragma unroll
      for (int m = 0; m < 4; m++) {
        f32x4 z = {};
        sc[m] = __builtin_amdgcn_mfma_f32_16x16x32_bf16(ka[0][m], qb[g][0], z, 0, 0, 0);
        sc[m] = __builtin_amdgcn_mfma_f32_16x16x32_bf16(ka[1][m], qb[g][1], sc[m], 0, 0, 0);
      }
      bf16x8 pa0, pa1;
#pragma unroll
      for (int m = 0; m < 2; m++)
#pragma unroll
        for (int r = 0; r < 4; r++)
          pa0[m * 4 + r] = (bf16)__builtin_amdgcn_exp2f(sc[m][r] * 0.1803368801f);
#pragma unroll
      for (int m = 0; m < 2; m++)
#pragma unroll
        for (int r = 0; r < 4; r++)
          pa1[m * 4 + r] = (bf16)__builtin_amdgcn_exp2f(sc[2 + m][r] * 0.1803368801f);
#pragma unroll
      for (int nd = 0; nd < 4; nd++) {
        oacc[g][nd] = __builtin_amdgcn_mfma_f32_16x16x32_bf16(pa0, vb[0][nd], oacc[g][nd], 0, 0, 0);
        oacc[g][nd] = __builtin_amdgcn_mfma_f32_16x16x32_bf16(pa1, vb[1][nd], oacc[g][nd], 0, 0, 0);
      }
      lacc[g] = __builtin_amdgcn_mfma_f32_16x16x32_bf16(pa0, onesb, lacc[g], 0, 0, 0);
      lacc[g] = __builtin_amdgcn_mfma_f32_16x16x32_bf16(pa1, onesb, lacc[g], 0, 0, 0);
    }
  }
#pragma unroll
  for (int g = 0; g < 4; g++) {
#pragma unroll
    for (int r = 0; r < 4; r++) {
      const float inv = 1.0f / lacc[g][r];
      const size_t row = rowbase + q0 + wave * 64 + g * 16 + lq * 4 + r;
#pragma unroll
      for (int nd = 0; nd < 4; nd++)
        out[row * 1024 + h * 64 + nd * 16 + l16] = (bf16)(oacc[g][nd][r] * inv);
    }
  }
}

// ---------------------------------------------------------------------------
extern "C" void kernel_launch(void* const* d_in, const int* in_sizes, int n_in,
                              void* d_out, int out_size, void* d_ws, size_t ws_size,
                              hipStream_t stream) {
  const float* x      = (const float*)d_in[0];
  const float* wq     = (const float*)d_in[1];
  const float* bq     = (const float*)d_in[2];
  const float* wk     = (const float*)d_in[3];
  const float* bk     = (const float*)d_in[4];
  const float* wv     = (const float*)d_in[5];
  const float* bv     = (const float*)d_in[6];
  const float* wo     = (const float*)d_in[7];
  const float* bo     = (const float*)d_in[8];
  const float* w1     = (const float*)d_in[9];
  const float* b1     = (const float*)d_in[10];
  const float* w2     = (const float*)d_in[11];
  const float* b2     = (const float*)d_in[12];
  const float* alpha1 = (const float*)d_in[13];
  const float* bias1  = (const float*)d_in[14];
  const float* alpha2 = (const float*)d_in[15];
  const float* bias2  = (const float*)d_in[16];
  float* out = (float*)d_out;  // h lives here, then final output

  const size_t MB = 1024ull * 1024ull;
  char* ws = (char*)d_ws;
  bf16*  wqkvT = (bf16*)(ws);                 // [3072][1024]   6 MB
  bf16*  woT   = (bf16*)(ws + 6 * MB);        // [1024][1024]   2 MB
  bf16*  w1T   = (bf16*)(ws + 8 * MB);        // [4096][1024]   8 MB
  bf16*  w2T   = (bf16*)(ws + 16 * MB);       // [1024][4096]   8 MB
  float* bqkv  = (float*)(ws + 24 * MB);      // [3072]
  bf16*  Z     = (bf16*)(ws + 24 * MB + 65536);   // [8192][1024] 16 MB (z1, Vt, z2)
  bf16*  Vtb   = Z;                                // Vt overlays dead z1
  bf16*  QKV   = (bf16*)(ws + 40 * MB + 65536);   // [8192][3072] 48 MB
  bf16*  AO    = (bf16*)(ws + 88 * MB + 65536);   // [8192][1024] 16 MB
  bf16*  FFN1  = QKV;  // [8192][4096] 64 MB, overlays dead QKV+AO region

  const dim3 tb(32, 8);
  transpose_cvt<<<dim3(32, 32), tb, 0, stream>>>(wq, wqkvT, 1024, 1024);
  transpose_cvt<<<dim3(32, 32), tb, 0, stream>>>(wk, wqkvT + 1024 * 1024, 1024, 1024);
  transpose_cvt<<<dim3(32, 32), tb, 0, stream>>>(wv, wqkvT + 2 * 1024 * 1024, 1024, 1024);
  transpose_cvt<<<dim3(32, 32), tb, 0, stream>>>(wo, woT, 1024, 1024);
  transpose_cvt<<<dim3(128, 32), tb, 0, stream>>>(w1, w1T, 1024, 4096);
  transpose_cvt<<<dim3(32, 128), tb, 0, stream>>>(w2, w2T, 4096, 1024);
  concat_bias<<<12, 256, 0, stream>>>(bq, bk, bv, bqkv);

  // LN1 -> z1
  ln_kernel<<<8192, 256, 0, stream>>>(x, Z, alpha1, bias1);
  // QKV = z1 @ [wq|wk|wv] + [bq|bk|bv]
  gemm_bt<bf16, false, false><<<dim3(64, 24), 256, 0, stream>>>(
      Z, wqkvT, bqkv, nullptr, QKV, 8192, 3072, 1024);
  // V^T (overlays dead z1)
  vt_prep<<<dim3(32, 64), 256, 0, stream>>>(QKV, Vtb);
  // attention -> AO
  attn_kernel<<<dim3(8, 64), 256, 0, stream>>>(QKV, Vtb, AO);
  // h = x + AO @ wo + bo   (h in d_out)
  gemm_bt<float, false, true><<<dim3(64, 8), 256, 0, stream>>>(
      AO, woT, bo, x, out, 8192, 1024, 1024);
  // LN2 -> z2
  ln_kernel<<<8192, 256, 0, stream>>>(out, Z, alpha2, bias2);
  // ffn1 = relu(z2 @ w1 + b1)
  gemm_bt<bf16, true, false><<<dim3(64, 32), 256, 0, stream>>>(
      Z, w1T, b1, nullptr, FFN1, 8192, 4096, 1024);
  // out = h + ffn1 @ w2 + b2   (in-place on d_out)
  gemm_bt<float, false, true><<<dim3(64, 8), 256, 0, stream>>>(
      FFN1, w2T, b2, out, out, 8192, 1024, 4096);
}

// Round 4
// 373.044 us; speedup vs baseline: 1.7379x; 1.0225x over previous
//
#include <hip/hip_runtime.h>
#include <hip/hip_bf16.h>
#include <cstdint>
#include <cstddef>

typedef __bf16 bf16;
typedef __bf16 bf16x4 __attribute__((ext_vector_type(4)));
typedef __bf16 bf16x8 __attribute__((ext_vector_type(8)));
typedef float f32x4 __attribute__((ext_vector_type(4)));

#define AS1 __attribute__((address_space(1)))
#define AS3 __attribute__((address_space(3)))

__device__ __forceinline__ void gload_lds16(const void* g, void* l) {
  __builtin_amdgcn_global_load_lds((AS1 void*)g, (AS3 void*)l, 16, 0, 0);
}

__device__ __forceinline__ float b2f(unsigned short u) {
  union { unsigned int i; float f; } v; v.i = (unsigned int)u << 16; return v.f;
}

// ---------------------------------------------------------------------------
// Transpose + fp32->bf16 convert: out[n][k] = (bf16) in[k][n].  in is [K][N].
__global__ __launch_bounds__(256)
void transpose_cvt(const float* __restrict__ in, bf16* __restrict__ out,
                   int K, int N) {
  __shared__ float t[32][33];
  const int tx = threadIdx.x, ty = threadIdx.y;
  const int n0 = blockIdx.x * 32, k0 = blockIdx.y * 32;
#pragma unroll
  for (int j = ty; j < 32; j += 8)
    t[j][tx] = in[(size_t)(k0 + j) * N + n0 + tx];
  __syncthreads();
#pragma unroll
  for (int j = ty; j < 32; j += 8)
    out[(size_t)(n0 + j) * K + k0 + tx] = (bf16)t[tx][j];
}

// ---------------------------------------------------------------------------
__global__ __launch_bounds__(256)
void concat_bias(const float* __restrict__ bq, const float* __restrict__ bk,
                 const float* __restrict__ bv, float* __restrict__ o) {
  int i = blockIdx.x * 256 + threadIdx.x;
  if (i < 1024) o[i] = bq[i];
  else if (i < 2048) o[i] = bk[i - 1024];
  else o[i] = bv[i - 2048];
}

// ---------------------------------------------------------------------------
// LayerNorm (torch semantics: ddof=1, eps on std), fp32 in -> bf16 out.
__global__ __launch_bounds__(256)
void ln_kernel(const float* __restrict__ x, bf16* __restrict__ y,
               const float* __restrict__ alpha_p, const float* __restrict__ beta_p) {
  const int row = blockIdx.x;
  const float4 v = ((const float4*)(x + (size_t)row * 1024))[threadIdx.x];
  float s = v.x + v.y + v.z + v.w;
  float ss = v.x * v.x + v.y * v.y + v.z * v.z + v.w * v.w;
#pragma unroll
  for (int m = 1; m < 64; m <<= 1) {
    s += __shfl_xor(s, m);
    ss += __shfl_xor(ss, m);
  }
  __shared__ float red[8];
  const int wave = threadIdx.x >> 6, lane = threadIdx.x & 63;
  if (lane == 0) { red[wave] = s; red[4 + wave] = ss; }
  __syncthreads();
  s = red[0] + red[1] + red[2] + red[3];
  ss = red[4] + red[5] + red[6] + red[7];
  const float mean = s * (1.0f / 1024.0f);
  const float var = fmaxf(ss - 1024.0f * mean * mean, 0.0f) * (1.0f / 1023.0f);
  const float k = alpha_p[0] / (sqrtf(var) + 1e-6f);
  const float beta = beta_p[0];
  union { bf16 b[4]; uint2 u; } pk;
  pk.b[0] = (bf16)((v.x - mean) * k + beta);
  pk.b[1] = (bf16)((v.y - mean) * k + beta);
  pk.b[2] = (bf16)((v.z - mean) * k + beta);
  pk.b[3] = (bf16)((v.w - mean) * k + beta);
  ((uint2*)(y + (size_t)row * 1024))[threadIdx.x] = pk.u;
}

// ---------------------------------------------------------------------------
// GEMM v3 (128x128, 2-phase) kept for WO (memory-floor-bound, small FLOP).
template <typename OutT, bool RELU, bool RESID>
__global__ __launch_bounds__(256)
void gemm_bt(const bf16* __restrict__ A, const bf16* __restrict__ Bt,
             const float* __restrict__ bias, const float* __restrict__ resid,
             OutT* __restrict__ C, int M, int N, int K) {
  __shared__ __align__(16) bf16 As[2][128 * 32];
  __shared__ __align__(16) bf16 Bs[2][128 * 32];
  const int tid = threadIdx.x;
  const int wave = tid >> 6, lane = tid & 63;
  const int l16 = lane & 15, lq = lane >> 4;
  const int nwg = gridDim.x * gridDim.y;
  const int id = blockIdx.y * gridDim.x + blockIdx.x;
  const int w = (id & 7) * (nwg >> 3) + (id >> 3);
  const int bm = (w / gridDim.y) * 128, bn = (w % gridDim.y) * 128;
  const int wr = wave >> 1, wc = wave & 1;

  const int tmp = (lane * 16) ^ (((lane >> 3) & 7) << 4);
  const int srow = tmp >> 6, sseg = (tmp >> 4) & 3;
  const bf16* Ab = A + (size_t)bm * K + sseg * 8;
  const bf16* Bb = Bt + (size_t)bn * K + sseg * 8;

  auto STAGE = [&](int k0, int buf) {
#pragma unroll
    for (int i = 0; i < 2; i++) {
      const int chunk = wave * 2 + i;
      const int r = chunk * 16 + srow;
      gload_lds16(Ab + (size_t)r * K + k0, (char*)As[buf] + chunk * 1024);
      gload_lds16(Bb + (size_t)r * K + k0, (char*)Bs[buf] + chunk * 1024);
    }
  };
  auto swz = [&](int row) -> int {
    return (row >> 1) * 128 + (((((row & 1) << 2) | lq) ^ ((row >> 1) & 7)) << 4);
  };

  STAGE(0, 0);
  __syncthreads();

  f32x4 acc[4][4] = {};
  const int nk = K >> 5;
  for (int t = 0; t < nk; t++) {
    const int cur = t & 1;
    if (t + 1 < nk) STAGE((t + 1) << 5, cur ^ 1);
    bf16x8 a[4], b[4];
#pragma unroll
    for (int m = 0; m < 4; m++)
      a[m] = *(const bf16x8*)((const char*)As[cur] + swz(wr * 64 + m * 16 + l16));
#pragma unroll
    for (int n = 0; n < 4; n++)
      b[n] = *(const bf16x8*)((const char*)Bs[cur] + swz(wc * 64 + n * 16 + l16));
#pragma unroll
    for (int m = 0; m < 4; m++)
#pragma unroll
      for (int n = 0; n < 4; n++)
        acc[m][n] = __builtin_amdgcn_mfma_f32_16x16x32_bf16(a[m], b[n], acc[m][n], 0, 0, 0);
    __syncthreads();
  }
#pragma unroll
  for (int m = 0; m < 4; m++) {
    const int row0 = bm + wr * 64 + m * 16 + lq * 4;
#pragma unroll
    for (int n = 0; n < 4; n++) {
      const int col = bn + wc * 64 + n * 16 + l16;
      const float bv = bias[col];
#pragma unroll
      for (int j = 0; j < 4; j++) {
        float v = acc[m][n][j] + bv;
        if (RELU) v = fmaxf(v, 0.0f);
        if (RESID) v += resid[(size_t)(row0 + j) * N + col];
        C[(size_t)(row0 + j) * N + col] = (OutT)v;
      }
    }
  }
}

// ---------------------------------------------------------------------------
// GEMM v4: 256x256 tile, BK=32, 8 waves (2Mx4N), 3-buffer LDS rotation with
// counted vmcnt(4) (T3/T4), phased barriers + setprio (T5), zero-conflict
// XOR-swizzled LDS (T2, both-sides), XCD-chunked grid (T1).
// C[M][N](ldc) = A(lda) @ Bt(ldb)^T [+bias][relu][+resid]; z-sliced for split-K.
template <typename OutT, bool RELU, bool BIAS>
__global__ __launch_bounds__(512, 2)
void gemm_v4(const bf16* __restrict__ A, const bf16* __restrict__ Bt,
             const float* __restrict__ bias, OutT* __restrict__ C,
             int lda, int ldb, int ldc, int K,
             int azs, int bzs, size_t czs) {
  __shared__ __align__(16) char lds[3 * 32768];  // 96 KB
  const int tid = threadIdx.x;
  const int wave = tid >> 6, lane = tid & 63;
  const int l16 = lane & 15, lq = lane >> 4;
  const int wr = wave >> 2, wc = wave & 3;
  const int nwg = gridDim.x * gridDim.y;
  const int id = blockIdx.y * gridDim.x + blockIdx.x;
  const int w = (id & 7) * (nwg >> 3) + (id >> 3);
  const int bm = (w / gridDim.y) * 256, bn = (w % gridDim.y) * 256;

  A  += (size_t)blockIdx.z * azs;
  Bt += (size_t)blockIdx.z * bzs;
  C  += (size_t)blockIdx.z * czs;

  // staging decomposition: lane -> (local row, seg) of its 16-row slice,
  // inverse of the read-side swizzle (key = lane>>3, proven r3)
  const int p = lane >> 3, jj = (lane & 7) ^ p;
  const int lrow = p * 2 + (jj >> 2), lseg = jj & 3;
  const bf16* Abase = A + (size_t)bm * lda + lseg * 8;
  const bf16* Bbase = Bt + (size_t)bn * ldb + lseg * 8;

  auto STAGEQ = [&](int t, int qq) {  // qq: 0,1 = A halves; 2,3 = B halves
    const int k0 = t << 5;
    const int grow = (qq & 1) * 128 + wave * 16 + lrow;
    const void* src = (qq < 2) ? (const void*)(Abase + (size_t)grow * lda + k0)
                               : (const void*)(Bbase + (size_t)grow * ldb + k0);
    gload_lds16(src, lds + (t % 3) * 32768 + qq * 8192 + wave * 1024);
  };
  auto swz = [&](int row) -> int {
    return (row >> 1) * 128 + (((((row & 1) << 2) | lq) ^ ((row >> 1) & 7)) << 4);
  };

  const int nk = K >> 5;
#pragma unroll
  for (int qq = 0; qq < 4; qq++) STAGEQ(0, qq);
#pragma unroll
  for (int qq = 0; qq < 4; qq++) STAGEQ(1, qq);

  f32x4 acc[8][4] = {};
  for (int t = 0; t < nk; t++) {
    const char* buf = lds + (t % 3) * 32768;
    // tile boundary: keep tile t+1's 4 loads in flight, tile t resident after
    if (t + 1 < nk) asm volatile("s_waitcnt vmcnt(4)" ::: "memory");
    else            asm volatile("s_waitcnt vmcnt(0)" ::: "memory");
    __builtin_amdgcn_s_barrier();            // B0: residency + WAR ordering
    // ---- phase A (mh=0) ----
    if (t + 2 < nk) { STAGEQ(t + 2, 0); STAGEQ(t + 2, 1); }
    bf16x8 a0[4], b0[4];
#pragma unroll
    for (int i = 0; i < 4; i++)
      a0[i] = *(const bf16x8*)(buf + swz(wr * 128 + i * 16 + l16));
#pragma unroll
    for (int n = 0; n < 4; n++)
      b0[n] = *(const bf16x8*)(buf + 16384 + swz(wc * 64 + n * 16 + l16));
    __builtin_amdgcn_s_barrier();            // B1
    asm volatile("s_waitcnt lgkmcnt(0)" ::: "memory");
    __builtin_amdgcn_sched_barrier(0);
    __builtin_amdgcn_s_setprio(1);
#pragma unroll
    for (int i = 0; i < 4; i++)
#pragma unroll
      for (int n = 0; n < 4; n++)
        acc[i][n] = __builtin_amdgcn_mfma_f32_16x16x32_bf16(a0[i], b0[n], acc[i][n], 0, 0, 0);
    __builtin_amdgcn_s_setprio(0);
    // ---- phase B (mh=1) ----
    if (t + 2 < nk) { STAGEQ(t + 2, 2); STAGEQ(t + 2, 3); }
    bf16x8 a1[4];
#pragma unroll
    for (int i = 0; i < 4; i++)
      a1[i] = *(const bf16x8*)(buf + swz(wr * 128 + 64 + i * 16 + l16));
    __builtin_amdgcn_s_barrier();            // B3
    asm volatile("s_waitcnt lgkmcnt(0)" ::: "memory");
    __builtin_amdgcn_sched_barrier(0);
    __builtin_amdgcn_s_setprio(1);
#pragma unroll
    for (int i = 0; i < 4; i++)
#pragma unroll
      for (int n = 0; n < 4; n++)
        acc[4 + i][n] = __builtin_amdgcn_mfma_f32_16x16x32_bf16(a1[i], b0[n], acc[4 + i][n], 0, 0, 0);
    __builtin_amdgcn_s_setprio(0);
  }
  // epilogue
#pragma unroll
  for (int m = 0; m < 8; m++) {
    const int row0 = bm + wr * 128 + m * 16 + lq * 4;
#pragma unroll
    for (int n = 0; n < 4; n++) {
      const int col = bn + wc * 64 + n * 16 + l16;
      const float bv = BIAS ? bias[col] : 0.0f;
#pragma unroll
      for (int j = 0; j < 4; j++) {
        float v = acc[m][n][j] + bv;
        if (RELU) v = fmaxf(v, 0.0f);
        C[(size_t)(row0 + j) * ldc + col] = (OutT)v;
      }
    }
  }
}

// ---------------------------------------------------------------------------
// FFN2 split-K reduce: out = out(h) + p0 + p1 + b2   over [8192][1024]
__global__ __launch_bounds__(256)
void ffn2_reduce(const bf16* __restrict__ p0, const bf16* __restrict__ p1,
                 const float* __restrict__ b2, float* __restrict__ out) {
  const size_t i = (size_t)blockIdx.x * 256 + threadIdx.x;  // 4 elems each
  float4 h = ((const float4*)out)[i];
  const ushort4 a = ((const ushort4*)p0)[i];
  const ushort4 b = ((const ushort4*)p1)[i];
  const float4 bb = ((const float4*)b2)[i & 255];
  h.x += b2f(a.x) + b2f(b.x) + bb.x;
  h.y += b2f(a.y) + b2f(b.y) + bb.y;
  h.z += b2f(a.z) + b2f(b.z) + bb.z;
  h.w += b2f(a.w) + b2f(b.w) + bb.w;
  ((float4*)out)[i] = h;
}

// ---------------------------------------------------------------------------
// V^T prep: Vt[bh*64 + d][s] = V[s][d] from QKV (V cols 2048 + h*64).
__global__ __launch_bounds__(256)
void vt_prep(const bf16* __restrict__ qkv, bf16* __restrict__ Vt) {
  __shared__ __align__(16) bf16 Vl[64 * 64];
  const int tid = threadIdx.x;
  const int sblk = blockIdx.x, bh = blockIdx.y, b = bh >> 4, h = bh & 15;
  const size_t srow = (size_t)b * 2048 + sblk * 64;
  const bf16* src = qkv + srow * 3072 + 2048 + h * 64;
#pragma unroll
  for (int i = 0; i < 2; i++) {
    int c = i * 256 + tid;
    int s = c >> 3, dseg = c & 7;
    int col = dseg ^ (s & 7) ^ (s >> 3);
    *(uint4*)((char*)Vl + s * 128 + col * 16) =
        *(const uint4*)(src + (size_t)s * 3072 + dseg * 8);
  }
  __syncthreads();
  bf16* dst = Vt + (size_t)bh * 64 * 2048 + sblk * 64;
#pragma unroll
  for (int i = 0; i < 2; i++) {
    int c = i * 256 + tid;
    int d = c >> 3, grp = c & 7;
    union { bf16 v[8]; uint4 u; } pk;
#pragma unroll
    for (int j = 0; j < 8; j++) {
      int s = grp * 8 + j;
      int col = (d >> 3) ^ (s & 7) ^ (s >> 3);
      pk.v[j] = *(const bf16*)((char*)Vl + s * 128 + col * 16 + ((2 * d) & 15));
    }
    *(uint4*)(dst + (size_t)d * 2048 + grp * 8) = pk.u;
  }
}

// ---------------------------------------------------------------------------
// Flash attention v2 (unchanged).
__global__ __launch_bounds__(256, 2)
void attn_kernel(const bf16* __restrict__ qkv, const bf16* __restrict__ Vt,
                 bf16* __restrict__ out) {
  __shared__ __align__(16) bf16 smem[32768];  // 64 KB
  bf16* Qs = smem;
  bf16* Ks = smem + 16384;
  bf16* Vs = smem + 24576;
  const int tid = threadIdx.x, wave = tid >> 6, lane = tid & 63;
  const int l16 = lane & 15, lq = lane >> 4;
  const int id = blockIdx.y * 8 + blockIdx.x;
  const int w = (id & 7) * 64 + (id >> 3);
  const int qblk = w & 7, bh = w >> 3;
  const int b = bh >> 4, h = bh & 15;
  const int q0 = qblk * 256;
  const size_t rowbase = (size_t)b * 2048;
  const bf16* Qg = qkv + (rowbase + q0) * 3072 + h * 64;
  const bf16* Kg = qkv + rowbase * 3072 + 1024 + h * 64;
  const bf16* Vg = Vt + (size_t)bh * 64 * 2048;

#pragma unroll
  for (int i = 0; i < 8; i++) {
    const int c = i * 256 + wave * 64;
    const int cl = c + lane;
    const int r = cl >> 3, seg = cl & 7;
    gload_lds16(Qg + (size_t)r * 3072 + (seg ^ (r & 7)) * 8, (char*)Qs + c * 16);
  }
  auto stageKV = [&](int kt, int buf) {
    const int kv0 = kt * 64;
#pragma unroll
    for (int i = 0; i < 2; i++) {
      const int c = i * 256 + wave * 64;
      const int cl = c + lane;
      const int r = cl >> 3, seg = cl & 7;
      gload_lds16(Kg + (size_t)(kv0 + r) * 3072 + (seg ^ (r & 7)) * 8,
                  (char*)Ks + buf * 8192 + c * 16);
      gload_lds16(Vg + (size_t)r * 2048 + kv0 + (seg ^ (r & 7)) * 8,
                  (char*)Vs + buf * 8192 + c * 16);
    }
  };
  stageKV(0, 0);

  f32x4 oacc[4][4] = {};
  f32x4 lacc[4] = {};
  bf16x8 qb[4][2];
  bf16x8 onesb;
#pragma unroll
  for (int j = 0; j < 8; j++) onesb[j] = (bf16)1.0f;

  for (int t = 0; t < 32; t++) {
    const int cur = t & 1;
    __builtin_amdgcn_s_barrier();
    if (t < 31) stageKV(t + 1, cur ^ 1);
    if (t < 31) asm volatile("s_waitcnt vmcnt(4)" ::: "memory");
    else        asm volatile("s_waitcnt vmcnt(0)" ::: "memory");
    __builtin_amdgcn_s_barrier();
    const char* Kb = (const char*)Ks + cur * 8192;
    const char* Vb = (const char*)Vs + cur * 8192;

    if (t == 0) {
#pragma unroll
      for (int g = 0; g < 4; g++)
#pragma unroll
        for (int H = 0; H < 2; H++) {
          const int row = wave * 64 + g * 16 + l16;
          const int col = (H * 64 + lq * 16) ^ ((row & 7) << 4);
          qb[g][H] = *(const bf16x8*)((const char*)Qs + row * 128 + col);
        }
    }
    bf16x8 ka[2][4];
#pragma unroll
    for (int H = 0; H < 2; H++)
#pragma unroll
      for (int m = 0; m < 4; m++) {
        const int row = m * 16 + l16;
        const int col = (H * 64 + lq * 16) ^ ((row & 7) << 4);
        ka[H][m] = *(const bf16x8*)(Kb + row * 128 + col);
      }
    bf16x8 vb[2][4];
#pragma unroll
    for (int H = 0; H < 2; H++)
#pragma unroll
      for (int nd = 0; nd < 4; nd++) {
        const int row = nd * 16 + l16;
        const int xorv = (row & 7) << 4;
        const int c1 = (H * 64 + lq * 8) ^ xorv;
        const int c2 = (H * 64 + lq * 8 + 32) ^ xorv;
        bf16x4 lo = *(const bf16x4*)(Vb + row * 128 + c1);
        bf16x4 hi = *(const bf16x4*)(Vb + row * 128 + c2);
        vb[H][nd] = __builtin_shufflevector(lo, hi, 0, 1, 2, 3, 4, 5, 6, 7);
      }
#pragma unroll
    for (int g = 0; g < 4; g++) {
      f32x4 sc[4];
#pragma unroll
      for (int m = 0; m < 4; m++) {
        f32x4 z = {};
        sc[m] = __builtin_amdgcn_mfma_f32_16x16x32_bf16(ka[0][m], qb[g][0], z, 0, 0, 0);
        sc[m] = __builtin_amdgcn_mfma_f32_16x16x32_bf16(ka[1][m], qb[g][1], sc[m], 0, 0, 0);
      }
      bf16x8 pa0, pa1;
#pragma unroll
      for (int m = 0; m < 2; m++)
#pragma unroll
        for (int r = 0; r < 4; r++)
          pa0[m * 4 + r] = (bf16)__builtin_amdgcn_exp2f(sc[m][r] * 0.1803368801f);
#pragma unroll
      for (int m = 0; m < 2; m++)
#pragma unroll
        for (int r = 0; r < 4; r++)
          pa1[m * 4 + r] = (bf16)__builtin_amdgcn_exp2f(sc[2 + m][r] * 0.1803368801f);
#pragma unroll
      for (int nd = 0; nd < 4; nd++) {
        oacc[g][nd] = __builtin_amdgcn_mfma_f32_16x16x32_bf16(pa0, vb[0][nd], oacc[g][nd], 0, 0, 0);
        oacc[g][nd] = __builtin_amdgcn_mfma_f32_16x16x32_bf16(pa1, vb[1][nd], oacc[g][nd], 0, 0, 0);
      }
      lacc[g] = __builtin_amdgcn_mfma_f32_16x16x32_bf16(pa0, onesb, lacc[g], 0, 0, 0);
      lacc[g] = __builtin_amdgcn_mfma_f32_16x16x32_bf16(pa1, onesb, lacc[g], 0, 0, 0);
    }
  }
#pragma unroll
  for (int g = 0; g < 4; g++) {
#pragma unroll
    for (int r = 0; r < 4; r++) {
      const float inv = 1.0f / lacc[g][r];
      const size_t row = rowbase + q0 + wave * 64 + g * 16 + lq * 4 + r;
#pragma unroll
      for (int nd = 0; nd < 4; nd++)
        out[row * 1024 + h * 64 + nd * 16 + l16] = (bf16)(oacc[g][nd][r] * inv);
    }
  }
}

// ---------------------------------------------------------------------------
extern "C" void kernel_launch(void* const* d_in, const int* in_sizes, int n_in,
                              void* d_out, int out_size, void* d_ws, size_t ws_size,
                              hipStream_t stream) {
  const float* x      = (const float*)d_in[0];
  const float* wq     = (const float*)d_in[1];
  const float* bq     = (const float*)d_in[2];
  const float* wk     = (const float*)d_in[3];
  const float* bk     = (const float*)d_in[4];
  const float* wv     = (const float*)d_in[5];
  const float* bv     = (const float*)d_in[6];
  const float* wo     = (const float*)d_in[7];
  const float* bo     = (const float*)d_in[8];
  const float* w1     = (const float*)d_in[9];
  const float* b1     = (const float*)d_in[10];
  const float* w2     = (const float*)d_in[11];
  const float* b2     = (const float*)d_in[12];
  const float* alpha1 = (const float*)d_in[13];
  const float* bias1  = (const float*)d_in[14];
  const float* alpha2 = (const float*)d_in[15];
  const float* bias2  = (const float*)d_in[16];
  float* out = (float*)d_out;  // h lives here, then final output

  const size_t MB = 1024ull * 1024ull;
  char* ws = (char*)d_ws;
  bf16*  wqkvT = (bf16*)(ws);                 // [3072][1024]   6 MB
  bf16*  woT   = (bf16*)(ws + 6 * MB);        // [1024][1024]   2 MB
  bf16*  w1T   = (bf16*)(ws + 8 * MB);        // [4096][1024]   8 MB
  bf16*  w2T   = (bf16*)(ws + 16 * MB);       // [1024][4096]   8 MB
  float* bqkv  = (float*)(ws + 24 * MB);      // [3072]
  bf16*  Z     = (bf16*)(ws + 24 * MB + 65536);   // [8192][1024] 16 MB (z1, Vt, z2, part1)
  bf16*  Vtb   = Z;
  bf16*  QKV   = (bf16*)(ws + 40 * MB + 65536);   // [8192][3072] 48 MB
  bf16*  AO    = (bf16*)(ws + 88 * MB + 65536);   // [8192][1024] 16 MB
  bf16*  FFN1  = QKV;  // [8192][4096] 64 MB, overlays dead QKV+AO region
  bf16*  PART  = (bf16*)ws;  // split-K partial 0: [8192][1024] 16 MB over dead weights
  const size_t PART1_OFF = (24 * MB + 65536) / 2;  // partial 1 -> Z region (elems)

  const dim3 tb(32, 8);
  transpose_cvt<<<dim3(32, 32), tb, 0, stream>>>(wq, wqkvT, 1024, 1024);
  transpose_cvt<<<dim3(32, 32), tb, 0, stream>>>(wk, wqkvT + 1024 * 1024, 1024, 1024);
  transpose_cvt<<<dim3(32, 32), tb, 0, stream>>>(wv, wqkvT + 2 * 1024 * 1024, 1024, 1024);
  transpose_cvt<<<dim3(32, 32), tb, 0, stream>>>(wo, woT, 1024, 1024);
  transpose_cvt<<<dim3(128, 32), tb, 0, stream>>>(w1, w1T, 1024, 4096);
  transpose_cvt<<<dim3(32, 128), tb, 0, stream>>>(w2, w2T, 4096, 1024);
  concat_bias<<<12, 256, 0, stream>>>(bq, bk, bv, bqkv);

  // LN1 -> z1
  ln_kernel<<<8192, 256, 0, stream>>>(x, Z, alpha1, bias1);
  // QKV = z1 @ [wq|wk|wv] + [bq|bk|bv]
  gemm_v4<bf16, false, true><<<dim3(32, 12), 512, 0, stream>>>(
      Z, wqkvT, bqkv, QKV, 1024, 1024, 3072, 1024, 0, 0, 0);
  // V^T (overlays dead z1)
  vt_prep<<<dim3(32, 64), 256, 0, stream>>>(QKV, Vtb);
  // attention -> AO
  attn_kernel<<<dim3(8, 64), 256, 0, stream>>>(QKV, Vtb, AO);
  // h = x + AO @ wo + bo   (h in d_out)
  gemm_bt<float, false, true><<<dim3(64, 8), 256, 0, stream>>>(
      AO, woT, bo, x, out, 8192, 1024, 1024);
  // LN2 -> z2
  ln_kernel<<<8192, 256, 0, stream>>>(out, Z, alpha2, bias2);
  // ffn1 = relu(z2 @ w1 + b1)
  gemm_v4<bf16, true, true><<<dim3(32, 16), 512, 0, stream>>>(
      Z, w1T, b1, FFN1, 1024, 1024, 4096, 1024, 0, 0, 0);
  // ffn2 partials: part[z] = FFN1[:, z*2048:] @ w2T[:, z*2048:]^T  (split-K)
  gemm_v4<bf16, false, false><<<dim3(32, 4, 2), 512, 0, stream>>>(
      FFN1, w2T, nullptr, PART, 4096, 4096, 1024, 2048, 2048, 2048, PART1_OFF);
  // out = h + part0 + part1 + b2
  ffn2_reduce<<<8192, 256, 0, stream>>>(PART, PART + PART1_OFF, b2, out);
}

// Round 5
// 370.575 us; speedup vs baseline: 1.7495x; 1.0067x over previous
//
#include <hip/hip_runtime.h>
#include <hip/hip_bf16.h>
#include <cstdint>
#include <cstddef>

typedef __bf16 bf16;
typedef __bf16 bf16x4 __attribute__((ext_vector_type(4)));
typedef __bf16 bf16x8 __attribute__((ext_vector_type(8)));
typedef float f32x4 __attribute__((ext_vector_type(4)));

#define AS1 __attribute__((address_space(1)))
#define AS3 __attribute__((address_space(3)))

__device__ __forceinline__ void gload_lds16(const void* g, void* l) {
  __builtin_amdgcn_global_load_lds((AS1 void*)g, (AS3 void*)l, 16, 0, 0);
}

__device__ __forceinline__ float b2f(unsigned short u) {
  union { unsigned int i; float f; } v; v.i = (unsigned int)u << 16; return v.f;
}

// ---------------------------------------------------------------------------
// Transpose + fp32->bf16 convert: out[n][k] = (bf16) in[k][n].  in is [K][N].
__global__ __launch_bounds__(256)
void transpose_cvt(const float* __restrict__ in, bf16* __restrict__ out,
                   int K, int N) {
  __shared__ float t[32][33];
  const int tx = threadIdx.x, ty = threadIdx.y;
  const int n0 = blockIdx.x * 32, k0 = blockIdx.y * 32;
#pragma unroll
  for (int j = ty; j < 32; j += 8)
    t[j][tx] = in[(size_t)(k0 + j) * N + n0 + tx];
  __syncthreads();
#pragma unroll
  for (int j = ty; j < 32; j += 8)
    out[(size_t)(n0 + j) * K + k0 + tx] = (bf16)t[tx][j];
}

// ---------------------------------------------------------------------------
__global__ __launch_bounds__(256)
void concat_bias(const float* __restrict__ bq, const float* __restrict__ bk,
                 const float* __restrict__ bv, float* __restrict__ o) {
  int i = blockIdx.x * 256 + threadIdx.x;
  if (i < 1024) o[i] = bq[i];
  else if (i < 2048) o[i] = bk[i - 1024];
  else o[i] = bv[i - 2048];
}

// ---------------------------------------------------------------------------
// LayerNorm (torch semantics: ddof=1, eps on std), fp32 in -> bf16 out.
__global__ __launch_bounds__(256)
void ln_kernel(const float* __restrict__ x, bf16* __restrict__ y,
               const float* __restrict__ alpha_p, const float* __restrict__ beta_p) {
  const int row = blockIdx.x;
  const float4 v = ((const float4*)(x + (size_t)row * 1024))[threadIdx.x];
  float s = v.x + v.y + v.z + v.w;
  float ss = v.x * v.x + v.y * v.y + v.z * v.z + v.w * v.w;
#pragma unroll
  for (int m = 1; m < 64; m <<= 1) {
    s += __shfl_xor(s, m);
    ss += __shfl_xor(ss, m);
  }
  __shared__ float red[8];
  const int wave = threadIdx.x >> 6, lane = threadIdx.x & 63;
  if (lane == 0) { red[wave] = s; red[4 + wave] = ss; }
  __syncthreads();
  s = red[0] + red[1] + red[2] + red[3];
  ss = red[4] + red[5] + red[6] + red[7];
  const float mean = s * (1.0f / 1024.0f);
  const float var = fmaxf(ss - 1024.0f * mean * mean, 0.0f) * (1.0f / 1023.0f);
  const float k = alpha_p[0] / (sqrtf(var) + 1e-6f);
  const float beta = beta_p[0];
  union { bf16 b[4]; uint2 u; } pk;
  pk.b[0] = (bf16)((v.x - mean) * k + beta);
  pk.b[1] = (bf16)((v.y - mean) * k + beta);
  pk.b[2] = (bf16)((v.z - mean) * k + beta);
  pk.b[3] = (bf16)((v.w - mean) * k + beta);
  ((uint2*)(y + (size_t)row * 1024))[threadIdx.x] = pk.u;
}

// ---------------------------------------------------------------------------
// GEMM v3 (128x128, 2-phase) kept for WO (memory-floor-bound, small FLOP).
template <typename OutT, bool RELU, bool RESID>
__global__ __launch_bounds__(256)
void gemm_bt(const bf16* __restrict__ A, const bf16* __restrict__ Bt,
             const float* __restrict__ bias, const float* __restrict__ resid,
             OutT* __restrict__ C, int M, int N, int K) {
  __shared__ __align__(16) bf16 As[2][128 * 32];
  __shared__ __align__(16) bf16 Bs[2][128 * 32];
  const int tid = threadIdx.x;
  const int wave = tid >> 6, lane = tid & 63;
  const int l16 = lane & 15, lq = lane >> 4;
  const int nwg = gridDim.x * gridDim.y;
  const int id = blockIdx.y * gridDim.x + blockIdx.x;
  const int w = (id & 7) * (nwg >> 3) + (id >> 3);
  const int bm = (w / gridDim.y) * 128, bn = (w % gridDim.y) * 128;
  const int wr = wave >> 1, wc = wave & 1;

  const int tmp = (lane * 16) ^ (((lane >> 3) & 7) << 4);
  const int srow = tmp >> 6, sseg = (tmp >> 4) & 3;
  const bf16* Ab = A + (size_t)bm * K + sseg * 8;
  const bf16* Bb = Bt + (size_t)bn * K + sseg * 8;

  auto STAGE = [&](int k0, int buf) {
#pragma unroll
    for (int i = 0; i < 2; i++) {
      const int chunk = wave * 2 + i;
      const int r = chunk * 16 + srow;
      gload_lds16(Ab + (size_t)r * K + k0, (char*)As[buf] + chunk * 1024);
      gload_lds16(Bb + (size_t)r * K + k0, (char*)Bs[buf] + chunk * 1024);
    }
  };
  auto swz = [&](int row) -> int {
    return (row >> 1) * 128 + (((((row & 1) << 2) | lq) ^ ((row >> 1) & 7)) << 4);
  };

  STAGE(0, 0);
  __syncthreads();

  f32x4 acc[4][4] = {};
  const int nk = K >> 5;
  for (int t = 0; t < nk; t++) {
    const int cur = t & 1;
    if (t + 1 < nk) STAGE((t + 1) << 5, cur ^ 1);
    bf16x8 a[4], b[4];
#pragma unroll
    for (int m = 0; m < 4; m++)
      a[m] = *(const bf16x8*)((const char*)As[cur] + swz(wr * 64 + m * 16 + l16));
#pragma unroll
    for (int n = 0; n < 4; n++)
      b[n] = *(const bf16x8*)((const char*)Bs[cur] + swz(wc * 64 + n * 16 + l16));
#pragma unroll
    for (int m = 0; m < 4; m++)
#pragma unroll
      for (int n = 0; n < 4; n++)
        acc[m][n] = __builtin_amdgcn_mfma_f32_16x16x32_bf16(a[m], b[n], acc[m][n], 0, 0, 0);
    __syncthreads();
  }
#pragma unroll
  for (int m = 0; m < 4; m++) {
    const int row0 = bm + wr * 64 + m * 16 + lq * 4;
#pragma unroll
    for (int n = 0; n < 4; n++) {
      const int col = bn + wc * 64 + n * 16 + l16;
      const float bv = bias[col];
#pragma unroll
      for (int j = 0; j < 4; j++) {
        float v = acc[m][n][j] + bv;
        if (RELU) v = fmaxf(v, 0.0f);
        if (RESID) v += resid[(size_t)(row0 + j) * N + col];
        C[(size_t)(row0 + j) * N + col] = (OutT)v;
      }
    }
  }
}

// ---------------------------------------------------------------------------
// GEMM v4r2: 256x256 tile, BK=32, 8 waves, 3-buffer LDS rotation, ONE barrier
// per K-tile, counted vmcnt(4) (never drains in steady state), counted
// lgkmcnt via compiler, setprio'd MFMA clusters, zero-conflict XOR swizzle.
template <typename OutT, bool RELU, bool BIAS>
__global__ __launch_bounds__(512, 2)
void gemm_v4(const bf16* __restrict__ A, const bf16* __restrict__ Bt,
             const float* __restrict__ bias, OutT* __restrict__ C,
             int lda, int ldb, int ldc, int K,
             int azs, int bzs, size_t czs) {
  __shared__ __align__(16) char lds[3 * 32768];  // 96 KB
  const int tid = threadIdx.x;
  const int wave = tid >> 6, lane = tid & 63;
  const int l16 = lane & 15, lq = lane >> 4;
  const int wr = wave >> 2, wc = wave & 3;
  const int nwg = gridDim.x * gridDim.y;
  const int id = blockIdx.y * gridDim.x + blockIdx.x;
  const int w = (id & 7) * (nwg >> 3) + (id >> 3);
  const int bm = (w / gridDim.y) * 256, bn = (w % gridDim.y) * 256;

  A  += (size_t)blockIdx.z * azs;
  Bt += (size_t)blockIdx.z * bzs;
  C  += (size_t)blockIdx.z * czs;

  const int p = lane >> 3, jj = (lane & 7) ^ p;
  const int lrow = p * 2 + (jj >> 2), lseg = jj & 3;
  const bf16* Abase = A + (size_t)bm * lda + lseg * 8;
  const bf16* Bbase = Bt + (size_t)bn * ldb + lseg * 8;

  auto STAGEQ = [&](int t, int qq) {  // qq: 0,1 = A halves; 2,3 = B halves
    const int k0 = t << 5;
    const int grow = (qq & 1) * 128 + wave * 16 + lrow;
    const void* src = (qq < 2) ? (const void*)(Abase + (size_t)grow * lda + k0)
                               : (const void*)(Bbase + (size_t)grow * ldb + k0);
    gload_lds16(src, lds + (t % 3) * 32768 + qq * 8192 + wave * 1024);
  };
  auto swz = [&](int row) -> int {
    return (row >> 1) * 128 + (((((row & 1) << 2) | lq) ^ ((row >> 1) & 7)) << 4);
  };

  const int nk = K >> 5;
#pragma unroll
  for (int qq = 0; qq < 4; qq++) STAGEQ(0, qq);
#pragma unroll
  for (int qq = 0; qq < 4; qq++) STAGEQ(1, qq);

  f32x4 acc[8][4] = {};
  for (int t = 0; t < nk; t++) {
    const char* buf = lds + (t % 3) * 32768;
    // own 4 loads of tile t done; tile t+1's 4 stay in flight (others' loads
    // covered by their identical wait + the barrier)
    if (t + 1 < nk) asm volatile("s_waitcnt vmcnt(4)" ::: "memory");
    else            asm volatile("s_waitcnt vmcnt(0)" ::: "memory");
    __builtin_amdgcn_s_barrier();
    __builtin_amdgcn_sched_barrier(0);
    if (t + 2 < nk) { STAGEQ(t + 2, 0); STAGEQ(t + 2, 1); }
    bf16x8 a0[4], b0[4], a1[4];
#pragma unroll
    for (int i = 0; i < 4; i++)
      a0[i] = *(const bf16x8*)(buf + swz(wr * 128 + i * 16 + l16));
#pragma unroll
    for (int n = 0; n < 4; n++)
      b0[n] = *(const bf16x8*)(buf + 16384 + swz(wc * 64 + n * 16 + l16));
    if (t + 2 < nk) { STAGEQ(t + 2, 2); STAGEQ(t + 2, 3); }
#pragma unroll
    for (int i = 0; i < 4; i++)
      a1[i] = *(const bf16x8*)(buf + swz(wr * 128 + 64 + i * 16 + l16));
    __builtin_amdgcn_sched_barrier(0);
    __builtin_amdgcn_s_setprio(1);
#pragma unroll
    for (int i = 0; i < 4; i++)
#pragma unroll
      for (int n = 0; n < 4; n++)
        acc[i][n] = __builtin_amdgcn_mfma_f32_16x16x32_bf16(a0[i], b0[n], acc[i][n], 0, 0, 0);
    __builtin_amdgcn_s_setprio(0);
    __builtin_amdgcn_sched_barrier(0);
    __builtin_amdgcn_s_setprio(1);
#pragma unroll
    for (int i = 0; i < 4; i++)
#pragma unroll
      for (int n = 0; n < 4; n++)
        acc[4 + i][n] = __builtin_amdgcn_mfma_f32_16x16x32_bf16(a1[i], b0[n], acc[4 + i][n], 0, 0, 0);
    __builtin_amdgcn_s_setprio(0);
  }
  // epilogue
#pragma unroll
  for (int m = 0; m < 8; m++) {
    const int row0 = bm + wr * 128 + m * 16 + lq * 4;
#pragma unroll
    for (int n = 0; n < 4; n++) {
      const int col = bn + wc * 64 + n * 16 + l16;
      const float bv = BIAS ? bias[col] : 0.0f;
#pragma unroll
      for (int j = 0; j < 4; j++) {
        float v = acc[m][n][j] + bv;
        if (RELU) v = fmaxf(v, 0.0f);
        C[(size_t)(row0 + j) * ldc + col] = (OutT)v;
      }
    }
  }
}

// ---------------------------------------------------------------------------
// FFN2 split-K reduce: out = out(h) + p0 + p1 + b2   over [8192][1024]
__global__ __launch_bounds__(256)
void ffn2_reduce(const bf16* __restrict__ p0, const bf16* __restrict__ p1,
                 const float* __restrict__ b2, float* __restrict__ out) {
  const size_t i = (size_t)blockIdx.x * 256 + threadIdx.x;
  float4 h = ((const float4*)out)[i];
  const ushort4 a = ((const ushort4*)p0)[i];
  const ushort4 b = ((const ushort4*)p1)[i];
  const float4 bb = ((const float4*)b2)[i & 255];
  h.x += b2f(a.x) + b2f(b.x) + bb.x;
  h.y += b2f(a.y) + b2f(b.y) + bb.y;
  h.z += b2f(a.z) + b2f(b.z) + bb.z;
  h.w += b2f(a.w) + b2f(b.w) + bb.w;
  ((float4*)out)[i] = h;
}

// ---------------------------------------------------------------------------
// V^T prep with PV k-permutation baked in:
//   stored position p (bits [H][lq1 lq0][j2 j1 j0]) holds kv = [H][j2][lq][j1 j0]
// so attn's PV B-fragment (H, lq) is 8 contiguous stored bf16 = one b128.
__global__ __launch_bounds__(256)
void vt_prep(const bf16* __restrict__ qkv, bf16* __restrict__ Vt) {
  __shared__ __align__(16) bf16 Vl[64 * 64];
  const int tid = threadIdx.x;
  const int sblk = blockIdx.x, bh = blockIdx.y, b = bh >> 4, h = bh & 15;
  const size_t srow = (size_t)b * 2048 + sblk * 64;
  const bf16* src = qkv + srow * 3072 + 2048 + h * 64;
#pragma unroll
  for (int i = 0; i < 2; i++) {
    int c = i * 256 + tid;
    int s = c >> 3, dseg = c & 7;
    int col = dseg ^ (s & 7) ^ (s >> 3);
    *(uint4*)((char*)Vl + s * 128 + col * 16) =
        *(const uint4*)(src + (size_t)s * 3072 + dseg * 8);
  }
  __syncthreads();
  bf16* dst = Vt + (size_t)bh * 64 * 2048 + sblk * 64;
#pragma unroll
  for (int i = 0; i < 2; i++) {
    int c = i * 256 + tid;
    int d = c >> 3, grp = c & 7;
    union { bf16 v[8]; uint4 u; } pk;
#pragma unroll
    for (int j = 0; j < 8; j++) {
      int pp = grp * 8 + j;  // stored position within 64-kv tile
      int s = (pp & 32) | (((pp >> 2) & 1) << 4) | (((pp >> 3) & 3) << 2) | (pp & 3);
      int col = (d >> 3) ^ (s & 7) ^ (s >> 3);
      pk.v[j] = *(const bf16*)((char*)Vl + s * 128 + col * 16 + ((2 * d) & 15));
    }
    *(uint4*)(dst + (size_t)d * 2048 + grp * 8) = pk.u;
  }
}

// ---------------------------------------------------------------------------
// Flash attention v3: 3-buffer KV rotation, distance-2 prefetch, ONE barrier
// per tile, counted vmcnt(4); V-perm -> single-b128 PV fragments; setprio'd
// MFMA clusters; fixed-max softmax; L via ones-MFMA.
__global__ __launch_bounds__(256, 2)
void attn_kernel(const bf16* __restrict__ qkv, const bf16* __restrict__ Vt,
                 bf16* __restrict__ out) {
  __shared__ __align__(16) bf16 smem[40960];  // 80 KB
  bf16* Qs = smem;             // [256 rows][64] swizzled, 32 KB
  bf16* Ks = smem + 16384;     // 3 x [64][64]  24 KB
  bf16* Vs = smem + 28672;     // 3 x [64][64]  24 KB (rows=d, cols=perm kv)
  const int tid = threadIdx.x, wave = tid >> 6, lane = tid & 63;
  const int l16 = lane & 15, lq = lane >> 4;
  const int id = blockIdx.y * 8 + blockIdx.x;
  const int w = (id & 7) * 64 + (id >> 3);
  const int qblk = w & 7, bh = w >> 3;
  const int b = bh >> 4, h = bh & 15;
  const int q0 = qblk * 256;
  const size_t rowbase = (size_t)b * 2048;
  const bf16* Qg = qkv + (rowbase + q0) * 3072 + h * 64;
  const bf16* Kg = qkv + rowbase * 3072 + 1024 + h * 64;
  const bf16* Vg = Vt + (size_t)bh * 64 * 2048;

#pragma unroll
  for (int i = 0; i < 8; i++) {
    const int c = i * 256 + wave * 64;
    const int cl = c + lane;
    const int r = cl >> 3, seg = cl & 7;
    gload_lds16(Qg + (size_t)r * 3072 + (seg ^ (r & 7)) * 8, (char*)Qs + c * 16);
  }
  auto stageKV = [&](int kt, int buf) {
    const int kv0 = kt * 64;
#pragma unroll
    for (int i = 0; i < 2; i++) {
      const int c = i * 256 + wave * 64;
      const int cl = c + lane;
      const int r = cl >> 3, seg = cl & 7;
      gload_lds16(Kg + (size_t)(kv0 + r) * 3072 + (seg ^ (r & 7)) * 8,
                  (char*)Ks + buf * 8192 + c * 16);
      gload_lds16(Vg + (size_t)r * 2048 + kv0 + (seg ^ (r & 7)) * 8,
                  (char*)Vs + buf * 8192 + c * 16);
    }
  };
  stageKV(0, 0);
  stageKV(1, 1);

  f32x4 oacc[4][4] = {};
  f32x4 lacc[4] = {};
  bf16x8 qb[4][2];
  bf16x8 onesb;
#pragma unroll
  for (int j = 0; j < 8; j++) onesb[j] = (bf16)1.0f;

  for (int t = 0; t < 32; t++) {
    // own tile-t loads done (4 of t+1 in flight); barrier closes cross-wave
    // RAW (others' tile-t loads) and WAR (buf[(t+2)%3]'s old readers).
    if (t < 31) asm volatile("s_waitcnt vmcnt(4)" ::: "memory");
    else        asm volatile("s_waitcnt vmcnt(0)" ::: "memory");
    __builtin_amdgcn_s_barrier();
    __builtin_amdgcn_sched_barrier(0);
    if (t + 2 < 32) stageKV(t + 2, (t + 2) % 3);
    const char* Kb = (const char*)Ks + (t % 3) * 8192;
    const char* Vb = (const char*)Vs + (t % 3) * 8192;

    if (t == 0) {  // Q fragments (B-operand: row q = wave*64+g*16+l16)
#pragma unroll
      for (int g = 0; g < 4; g++)
#pragma unroll
        for (int H = 0; H < 2; H++) {
          const int row = wave * 64 + g * 16 + l16;
          const int col = (H * 64 + lq * 16) ^ ((row & 7) << 4);
          qb[g][H] = *(const bf16x8*)((const char*)Qs + row * 128 + col);
        }
    }
    bf16x8 ka[2][4];
#pragma unroll
    for (int H = 0; H < 2; H++)
#pragma unroll
      for (int m = 0; m < 4; m++) {
        const int row = m * 16 + l16;
        const int col = (H * 64 + lq * 16) ^ ((row & 7) << 4);
        ka[H][m] = *(const bf16x8*)(Kb + row * 128 + col);
      }
    bf16x8 vb[2][4];
#pragma unroll
    for (int H = 0; H < 2; H++)
#pragma unroll
      for (int nd = 0; nd < 4; nd++) {
        const int row = nd * 16 + l16;
        const int col = (H * 64 + lq * 16) ^ ((row & 7) << 4);
        vb[H][nd] = *(const bf16x8*)(Vb + row * 128 + col);
      }
#pragma unroll
    for (int g = 0; g < 4; g++) {
      f32x4 sc[4];
      __builtin_amdgcn_s_setprio(1);
#pragma unroll
      for (int m = 0; m < 4; m++) {
        f32x4 z = {};
        sc[m] = __builtin_amdgcn_mfma_f32_16x16x32_bf16(ka[0][m], qb[g][0], z, 0, 0, 0);
        sc[m] = __builtin_amdgcn_mfma_f32_16x16x32_bf16(ka[1][m], qb[g][1], sc[m], 0, 0, 0);
      }
      __builtin_amdgcn_s_setprio(0);
      bf16x8 pa0, pa1;
#pragma unroll
      for (int m = 0; m < 2; m++)
#pragma unroll
        for (int r = 0; r < 4; r++)
          pa0[m * 4 + r] = (bf16)__builtin_amdgcn_exp2f(sc[m][r] * 0.1803368801f);
#pragma unroll
      for (int m = 0; m < 2; m++)
#pragma unroll
        for (int r = 0; r < 4; r++)
          pa1[m * 4 + r] = (bf16)__builtin_amdgcn_exp2f(sc[2 + m][r] * 0.1803368801f);
      __builtin_amdgcn_s_setprio(1);
#pragma unroll
      for (int nd = 0; nd < 4; nd++) {
        oacc[g][nd] = __builtin_amdgcn_mfma_f32_16x16x32_bf16(pa0, vb[0][nd], oacc[g][nd], 0, 0, 0);
        oacc[g][nd] = __builtin_amdgcn_mfma_f32_16x16x32_bf16(pa1, vb[1][nd], oacc[g][nd], 0, 0, 0);
      }
      lacc[g] = __builtin_amdgcn_mfma_f32_16x16x32_bf16(pa0, onesb, lacc[g], 0, 0, 0);
      lacc[g] = __builtin_amdgcn_mfma_f32_16x16x32_bf16(pa1, onesb, lacc[g], 0, 0, 0);
      __builtin_amdgcn_s_setprio(0);
    }
  }
#pragma unroll
  for (int g = 0; g < 4; g++) {
#pragma unroll
    for (int r = 0; r < 4; r++) {
      const float inv = 1.0f / lacc[g][r];
      const size_t row = rowbase + q0 + wave * 64 + g * 16 + lq * 4 + r;
#pragma unroll
      for (int nd = 0; nd < 4; nd++)
        out[row * 1024 + h * 64 + nd * 16 + l16] = (bf16)(oacc[g][nd][r] * inv);
    }
  }
}

// ---------------------------------------------------------------------------
extern "C" void kernel_launch(void* const* d_in, const int* in_sizes, int n_in,
                              void* d_out, int out_size, void* d_ws, size_t ws_size,
                              hipStream_t stream) {
  const float* x      = (const float*)d_in[0];
  const float* wq     = (const float*)d_in[1];
  const float* bq     = (const float*)d_in[2];
  const float* wk     = (const float*)d_in[3];
  const float* bk     = (const float*)d_in[4];
  const float* wv     = (const float*)d_in[5];
  const float* bv     = (const float*)d_in[6];
  const float* wo     = (const float*)d_in[7];
  const float* bo     = (const float*)d_in[8];
  const float* w1     = (const float*)d_in[9];
  const float* b1     = (const float*)d_in[10];
  const float* w2     = (const float*)d_in[11];
  const float* b2     = (const float*)d_in[12];
  const float* alpha1 = (const float*)d_in[13];
  const float* bias1  = (const float*)d_in[14];
  const float* alpha2 = (const float*)d_in[15];
  const float* bias2  = (const float*)d_in[16];
  float* out = (float*)d_out;  // h lives here, then final output

  const size_t MB = 1024ull * 1024ull;
  char* ws = (char*)d_ws;
  bf16*  wqkvT = (bf16*)(ws);                 // [3072][1024]   6 MB
  bf16*  woT   = (bf16*)(ws + 6 * MB);        // [1024][1024]   2 MB
  bf16*  w1T   = (bf16*)(ws + 8 * MB);        // [4096][1024]   8 MB
  bf16*  w2T   = (bf16*)(ws + 16 * MB);       // [1024][4096]   8 MB
  float* bqkv  = (float*)(ws + 24 * MB);      // [3072]
  bf16*  Z     = (bf16*)(ws + 24 * MB + 65536);   // [8192][1024] 16 MB (z1, Vt, z2, part1)
  bf16*  Vtb   = Z;
  bf16*  QKV   = (bf16*)(ws + 40 * MB + 65536);   // [8192][3072] 48 MB
  bf16*  AO    = (bf16*)(ws + 88 * MB + 65536);   // [8192][1024] 16 MB
  bf16*  FFN1  = QKV;  // [8192][4096] 64 MB, overlays dead QKV+AO region
  bf16*  PART  = (bf16*)ws;  // split-K partial 0 over dead weight transposes
  const size_t PART1_OFF = (24 * MB + 65536) / 2;  // partial 1 -> Z region (elems)

  const dim3 tb(32, 8);
  transpose_cvt<<<dim3(32, 32), tb, 0, stream>>>(wq, wqkvT, 1024, 1024);
  transpose_cvt<<<dim3(32, 32), tb, 0, stream>>>(wk, wqkvT + 1024 * 1024, 1024, 1024);
  transpose_cvt<<<dim3(32, 32), tb, 0, stream>>>(wv, wqkvT + 2 * 1024 * 1024, 1024, 1024);
  transpose_cvt<<<dim3(32, 32), tb, 0, stream>>>(wo, woT, 1024, 1024);
  transpose_cvt<<<dim3(128, 32), tb, 0, stream>>>(w1, w1T, 1024, 4096);
  transpose_cvt<<<dim3(32, 128), tb, 0, stream>>>(w2, w2T, 4096, 1024);
  concat_bias<<<12, 256, 0, stream>>>(bq, bk, bv, bqkv);

  // LN1 -> z1
  ln_kernel<<<8192, 256, 0, stream>>>(x, Z, alpha1, bias1);
  // QKV = z1 @ [wq|wk|wv] + [bq|bk|bv]
  gemm_v4<bf16, false, true><<<dim3(32, 12), 512, 0, stream>>>(
      Z, wqkvT, bqkv, QKV, 1024, 1024, 3072, 1024, 0, 0, 0);
  // V^T with PV k-perm (overlays dead z1)
  vt_prep<<<dim3(32, 64), 256, 0, stream>>>(QKV, Vtb);
  // attention -> AO
  attn_kernel<<<dim3(8, 64), 256, 0, stream>>>(QKV, Vtb, AO);
  // h = x + AO @ wo + bo   (h in d_out)
  gemm_bt<float, false, true><<<dim3(64, 8), 256, 0, stream>>>(
      AO, woT, bo, x, out, 8192, 1024, 1024);
  // LN2 -> z2
  ln_kernel<<<8192, 256, 0, stream>>>(out, Z, alpha2, bias2);
  // ffn1 = relu(z2 @ w1 + b1)
  gemm_v4<bf16, true, true><<<dim3(32, 16), 512, 0, stream>>>(
      Z, w1T, b1, FFN1, 1024, 1024, 4096, 1024, 0, 0, 0);
  // ffn2 partials: part[z] = FFN1[:, z*2048:] @ w2T[:, z*2048:]^T  (split-K)
  gemm_v4<bf16, false, false><<<dim3(32, 4, 2), 512, 0, stream>>>(
      FFN1, w2T, nullptr, PART, 4096, 4096, 1024, 2048, 2048, 2048, PART1_OFF);
  // out = h + part0 + part1 + b2
  ffn2_reduce<<<8192, 256, 0, stream>>>(PART, PART + PART1_OFF, b2, out);
}

// Round 6
// 351.990 us; speedup vs baseline: 1.8418x; 1.0528x over previous
//
#include <hip/hip_runtime.h>
#include <hip/hip_bf16.h>
#include <cstdint>
#include <cstddef>

typedef __bf16 bf16;
typedef __bf16 bf16x4 __attribute__((ext_vector_type(4)));
typedef __bf16 bf16x8 __attribute__((ext_vector_type(8)));
typedef float f32x4 __attribute__((ext_vector_type(4)));

// log2(e) / sqrt(64): folded into wq/bq so attn scores feed exp2 directly.
#define QK_SCALE 0.1803368801111204f

#define AS1 __attribute__((address_space(1)))
#define AS3 __attribute__((address_space(3)))

__device__ __forceinline__ void gload_lds16(const void* g, void* l) {
  __builtin_amdgcn_global_load_lds((AS1 void*)g, (AS3 void*)l, 16, 0, 0);
}

__device__ __forceinline__ float b2f(unsigned short u) {
  union { unsigned int i; float f; } v; v.i = (unsigned int)u << 16; return v.f;
}

// ---------------------------------------------------------------------------
// Transpose + fp32->bf16 convert: out[n][k] = (bf16) in[k][n].  in is [K][N].
__global__ __launch_bounds__(256)
void transpose_cvt(const float* __restrict__ in, bf16* __restrict__ out,
                   int K, int N) {
  __shared__ float t[32][33];
  const int tx = threadIdx.x, ty = threadIdx.y;
  const int n0 = blockIdx.x * 32, k0 = blockIdx.y * 32;
#pragma unroll
  for (int j = ty; j < 32; j += 8)
    t[j][tx] = in[(size_t)(k0 + j) * N + n0 + tx];
  __syncthreads();
#pragma unroll
  for (int j = ty; j < 32; j += 8)
    out[(size_t)(n0 + j) * K + k0 + tx] = (bf16)t[tx][j];
}

// Batched 1024x1024 transpose for wq/wk/wv/wo; wq gets QK_SCALE folded in.
__global__ __launch_bounds__(256)
void transpose_cvt4(const float* __restrict__ wq, const float* __restrict__ wk,
                    const float* __restrict__ wv, const float* __restrict__ wo,
                    bf16* __restrict__ wqkvT, bf16* __restrict__ woT) {
  __shared__ float t[32][33];
  const int tx = threadIdx.x, ty = threadIdx.y, z = blockIdx.z;
  const float* in = (z == 0) ? wq : (z == 1) ? wk : (z == 2) ? wv : wo;
  bf16* out = (z < 3) ? wqkvT + (size_t)z * 1024 * 1024 : woT;
  const float sc = (z == 0) ? QK_SCALE : 1.0f;
  const int n0 = blockIdx.x * 32, k0 = blockIdx.y * 32;
#pragma unroll
  for (int j = ty; j < 32; j += 8)
    t[j][tx] = in[(size_t)(k0 + j) * 1024 + n0 + tx] * sc;
  __syncthreads();
#pragma unroll
  for (int j = ty; j < 32; j += 8)
    out[(size_t)(n0 + j) * 1024 + k0 + tx] = (bf16)t[tx][j];
}

// ---------------------------------------------------------------------------
__global__ __launch_bounds__(256)
void concat_bias(const float* __restrict__ bq, const float* __restrict__ bk,
                 const float* __restrict__ bv, float* __restrict__ o) {
  int i = blockIdx.x * 256 + threadIdx.x;
  if (i < 1024) o[i] = bq[i] * QK_SCALE;
  else if (i < 2048) o[i] = bk[i - 1024];
  else o[i] = bv[i - 2048];
}

// ---------------------------------------------------------------------------
// LayerNorm (torch semantics: ddof=1, eps on std), fp32 in -> bf16 out.
__global__ __launch_bounds__(256)
void ln_kernel(const float* __restrict__ x, bf16* __restrict__ y,
               const float* __restrict__ alpha_p, const float* __restrict__ beta_p) {
  const int row = blockIdx.x;
  const float4 v = ((const float4*)(x + (size_t)row * 1024))[threadIdx.x];
  float s = v.x + v.y + v.z + v.w;
  float ss = v.x * v.x + v.y * v.y + v.z * v.z + v.w * v.w;
#pragma unroll
  for (int m = 1; m < 64; m <<= 1) {
    s += __shfl_xor(s, m);
    ss += __shfl_xor(ss, m);
  }
  __shared__ float red[8];
  const int wave = threadIdx.x >> 6, lane = threadIdx.x & 63;
  if (lane == 0) { red[wave] = s; red[4 + wave] = ss; }
  __syncthreads();
  s = red[0] + red[1] + red[2] + red[3];
  ss = red[4] + red[5] + red[6] + red[7];
  const float mean = s * (1.0f / 1024.0f);
  const float var = fmaxf(ss - 1024.0f * mean * mean, 0.0f) * (1.0f / 1023.0f);
  const float k = alpha_p[0] / (sqrtf(var) + 1e-6f);
  const float beta = beta_p[0];
  union { bf16 b[4]; uint2 u; } pk;
  pk.b[0] = (bf16)((v.x - mean) * k + beta);
  pk.b[1] = (bf16)((v.y - mean) * k + beta);
  pk.b[2] = (bf16)((v.z - mean) * k + beta);
  pk.b[3] = (bf16)((v.w - mean) * k + beta);
  ((uint2*)(y + (size_t)row * 1024))[threadIdx.x] = pk.u;
}

// ---------------------------------------------------------------------------
// GEMM v3 (128x128, 2-phase) kept for WO (memory-floor-bound, small FLOP).
template <typename OutT, bool RELU, bool RESID>
__global__ __launch_bounds__(256)
void gemm_bt(const bf16* __restrict__ A, const bf16* __restrict__ Bt,
             const float* __restrict__ bias, const float* __restrict__ resid,
             OutT* __restrict__ C, int M, int N, int K) {
  __shared__ __align__(16) bf16 As[2][128 * 32];
  __shared__ __align__(16) bf16 Bs[2][128 * 32];
  const int tid = threadIdx.x;
  const int wave = tid >> 6, lane = tid & 63;
  const int l16 = lane & 15, lq = lane >> 4;
  const int nwg = gridDim.x * gridDim.y;
  const int id = blockIdx.y * gridDim.x + blockIdx.x;
  const int w = (id & 7) * (nwg >> 3) + (id >> 3);
  const int bm = (w / gridDim.y) * 128, bn = (w % gridDim.y) * 128;
  const int wr = wave >> 1, wc = wave & 1;

  const int tmp = (lane * 16) ^ (((lane >> 3) & 7) << 4);
  const int srow = tmp >> 6, sseg = (tmp >> 4) & 3;
  const bf16* Ab = A + (size_t)bm * K + sseg * 8;
  const bf16* Bb = Bt + (size_t)bn * K + sseg * 8;

  auto STAGE = [&](int k0, int buf) {
#pragma unroll
    for (int i = 0; i < 2; i++) {
      const int chunk = wave * 2 + i;
      const int r = chunk * 16 + srow;
      gload_lds16(Ab + (size_t)r * K + k0, (char*)As[buf] + chunk * 1024);
      gload_lds16(Bb + (size_t)r * K + k0, (char*)Bs[buf] + chunk * 1024);
    }
  };
  auto swz = [&](int row) -> int {
    return (row >> 1) * 128 + (((((row & 1) << 2) | lq) ^ ((row >> 1) & 7)) << 4);
  };

  STAGE(0, 0);
  __syncthreads();

  f32x4 acc[4][4] = {};
  const int nk = K >> 5;
  for (int t = 0; t < nk; t++) {
    const int cur = t & 1;
    if (t + 1 < nk) STAGE((t + 1) << 5, cur ^ 1);
    bf16x8 a[4], b[4];
#pragma unroll
    for (int m = 0; m < 4; m++)
      a[m] = *(const bf16x8*)((const char*)As[cur] + swz(wr * 64 + m * 16 + l16));
#pragma unroll
    for (int n = 0; n < 4; n++)
      b[n] = *(const bf16x8*)((const char*)Bs[cur] + swz(wc * 64 + n * 16 + l16));
#pragma unroll
    for (int m = 0; m < 4; m++)
#pragma unroll
      for (int n = 0; n < 4; n++)
        acc[m][n] = __builtin_amdgcn_mfma_f32_16x16x32_bf16(a[m], b[n], acc[m][n], 0, 0, 0);
    __syncthreads();
  }
#pragma unroll
  for (int m = 0; m < 4; m++) {
    const int row0 = bm + wr * 64 + m * 16 + lq * 4;
#pragma unroll
    for (int n = 0; n < 4; n++) {
      const int col = bn + wc * 64 + n * 16 + l16;
      const float bv = bias[col];
#pragma unroll
      for (int j = 0; j < 4; j++) {
        float v = acc[m][n][j] + bv;
        if (RELU) v = fmaxf(v, 0.0f);
        if (RESID) v += resid[(size_t)(row0 + j) * N + col];
        C[(size_t)(row0 + j) * N + col] = (OutT)v;
      }
    }
  }
}

// ---------------------------------------------------------------------------
// GEMM v4r2: 256x256 tile, BK=32, 8 waves, 3-buffer LDS rotation, ONE barrier
// per K-tile, counted vmcnt(4), setprio'd MFMA clusters, zero-conflict swizzle.
template <typename OutT, bool RELU, bool BIAS>
__global__ __launch_bounds__(512, 2)
void gemm_v4(const bf16* __restrict__ A, const bf16* __restrict__ Bt,
             const float* __restrict__ bias, OutT* __restrict__ C,
             int lda, int ldb, int ldc, int K,
             int azs, int bzs, size_t czs) {
  __shared__ __align__(16) char lds[3 * 32768];  // 96 KB
  const int tid = threadIdx.x;
  const int wave = tid >> 6, lane = tid & 63;
  const int l16 = lane & 15, lq = lane >> 4;
  const int wr = wave >> 2, wc = wave & 3;
  const int nwg = gridDim.x * gridDim.y;
  const int id = blockIdx.y * gridDim.x + blockIdx.x;
  const int w = (id & 7) * (nwg >> 3) + (id >> 3);
  const int bm = (w / gridDim.y) * 256, bn = (w % gridDim.y) * 256;

  A  += (size_t)blockIdx.z * azs;
  Bt += (size_t)blockIdx.z * bzs;
  C  += (size_t)blockIdx.z * czs;

  const int p = lane >> 3, jj = (lane & 7) ^ p;
  const int lrow = p * 2 + (jj >> 2), lseg = jj & 3;
  const bf16* Abase = A + (size_t)bm * lda + lseg * 8;
  const bf16* Bbase = Bt + (size_t)bn * ldb + lseg * 8;

  auto STAGEQ = [&](int t, int qq) {  // qq: 0,1 = A halves; 2,3 = B halves
    const int k0 = t << 5;
    const int grow = (qq & 1) * 128 + wave * 16 + lrow;
    const void* src = (qq < 2) ? (const void*)(Abase + (size_t)grow * lda + k0)
                               : (const void*)(Bbase + (size_t)grow * ldb + k0);
    gload_lds16(src, lds + (t % 3) * 32768 + qq * 8192 + wave * 1024);
  };
  auto swz = [&](int row) -> int {
    return (row >> 1) * 128 + (((((row & 1) << 2) | lq) ^ ((row >> 1) & 7)) << 4);
  };

  const int nk = K >> 5;
#pragma unroll
  for (int qq = 0; qq < 4; qq++) STAGEQ(0, qq);
#pragma unroll
  for (int qq = 0; qq < 4; qq++) STAGEQ(1, qq);

  f32x4 acc[8][4] = {};
  for (int t = 0; t < nk; t++) {
    const char* buf = lds + (t % 3) * 32768;
    if (t + 1 < nk) asm volatile("s_waitcnt vmcnt(4)" ::: "memory");
    else            asm volatile("s_waitcnt vmcnt(0)" ::: "memory");
    __builtin_amdgcn_s_barrier();
    __builtin_amdgcn_sched_barrier(0);
    if (t + 2 < nk) { STAGEQ(t + 2, 0); STAGEQ(t + 2, 1); }
    bf16x8 a0[4], b0[4], a1[4];
#pragma unroll
    for (int i = 0; i < 4; i++)
      a0[i] = *(const bf16x8*)(buf + swz(wr * 128 + i * 16 + l16));
#pragma unroll
    for (int n = 0; n < 4; n++)
      b0[n] = *(const bf16x8*)(buf + 16384 + swz(wc * 64 + n * 16 + l16));
    if (t + 2 < nk) { STAGEQ(t + 2, 2); STAGEQ(t + 2, 3); }
#pragma unroll
    for (int i = 0; i < 4; i++)
      a1[i] = *(const bf16x8*)(buf + swz(wr * 128 + 64 + i * 16 + l16));
    __builtin_amdgcn_sched_barrier(0);
    __builtin_amdgcn_s_setprio(1);
#pragma unroll
    for (int i = 0; i < 4; i++)
#pragma unroll
      for (int n = 0; n < 4; n++)
        acc[i][n] = __builtin_amdgcn_mfma_f32_16x16x32_bf16(a0[i], b0[n], acc[i][n], 0, 0, 0);
    __builtin_amdgcn_s_setprio(0);
    __builtin_amdgcn_sched_barrier(0);
    __builtin_amdgcn_s_setprio(1);
#pragma unroll
    for (int i = 0; i < 4; i++)
#pragma unroll
      for (int n = 0; n < 4; n++)
        acc[4 + i][n] = __builtin_amdgcn_mfma_f32_16x16x32_bf16(a1[i], b0[n], acc[4 + i][n], 0, 0, 0);
    __builtin_amdgcn_s_setprio(0);
  }
#pragma unroll
  for (int m = 0; m < 8; m++) {
    const int row0 = bm + wr * 128 + m * 16 + lq * 4;
#pragma unroll
    for (int n = 0; n < 4; n++) {
      const int col = bn + wc * 64 + n * 16 + l16;
      const float bv = BIAS ? bias[col] : 0.0f;
#pragma unroll
      for (int j = 0; j < 4; j++) {
        float v = acc[m][n][j] + bv;
        if (RELU) v = fmaxf(v, 0.0f);
        C[(size_t)(row0 + j) * ldc + col] = (OutT)v;
      }
    }
  }
}

// ---------------------------------------------------------------------------
// FFN2 split-K reduce: out = out(h) + p0 + p1 + b2   over [8192][1024]
__global__ __launch_bounds__(256)
void ffn2_reduce(const bf16* __restrict__ p0, const bf16* __restrict__ p1,
                 const float* __restrict__ b2, float* __restrict__ out) {
  const size_t i = (size_t)blockIdx.x * 256 + threadIdx.x;
  float4 h = ((const float4*)out)[i];
  const ushort4 a = ((const ushort4*)p0)[i];
  const ushort4 b = ((const ushort4*)p1)[i];
  const float4 bb = ((const float4*)b2)[i & 255];
  h.x += b2f(a.x) + b2f(b.x) + bb.x;
  h.y += b2f(a.y) + b2f(b.y) + bb.y;
  h.z += b2f(a.z) + b2f(b.z) + bb.z;
  h.w += b2f(a.w) + b2f(b.w) + bb.w;
  ((float4*)out)[i] = h;
}

// ---------------------------------------------------------------------------
// V^T prep with PV k-permutation baked in:
//   stored position p (bits [H][lq1 lq0][j2 j1 j0]) holds kv = [H][j2][lq][j1 j0]
__global__ __launch_bounds__(256)
void vt_prep(const bf16* __restrict__ qkv, bf16* __restrict__ Vt) {
  __shared__ __align__(16) bf16 Vl[64 * 64];
  const int tid = threadIdx.x;
  const int sblk = blockIdx.x, bh = blockIdx.y, b = bh >> 4, h = bh & 15;
  const size_t srow = (size_t)b * 2048 + sblk * 64;
  const bf16* src = qkv + srow * 3072 + 2048 + h * 64;
#pragma unroll
  for (int i = 0; i < 2; i++) {
    int c = i * 256 + tid;
    int s = c >> 3, dseg = c & 7;
    int col = dseg ^ (s & 7) ^ (s >> 3);
    *(uint4*)((char*)Vl + s * 128 + col * 16) =
        *(const uint4*)(src + (size_t)s * 3072 + dseg * 8);
  }
  __syncthreads();
  bf16* dst = Vt + (size_t)bh * 64 * 2048 + sblk * 64;
#pragma unroll
  for (int i = 0; i < 2; i++) {
    int c = i * 256 + tid;
    int d = c >> 3, grp = c & 7;
    union { bf16 v[8]; uint4 u; } pk;
#pragma unroll
    for (int j = 0; j < 8; j++) {
      int pp = grp * 8 + j;  // stored position within 64-kv tile
      int s = (pp & 32) | (((pp >> 2) & 1) << 4) | (((pp >> 3) & 3) << 2) | (pp & 3);
      int col = (d >> 3) ^ (s & 7) ^ (s >> 3);
      pk.v[j] = *(const bf16*)((char*)Vl + s * 128 + col * 16 + ((2 * d) & 15));
    }
    *(uint4*)(dst + (size_t)d * 2048 + grp * 8) = pk.u;
  }
}

// ---------------------------------------------------------------------------
// Flash attention v3.1: Q pre-scaled by log2e/sqrt(dk) (exp2 direct), Q-frags
// hoisted to prologue (counted vmcnt), 3-buffer KV rotation, one barrier/tile,
// V-perm single-b128 PV fragments, setprio'd MFMA, fixed-max softmax, L=ones-MFMA.
__global__ __launch_bounds__(256, 2)
void attn_kernel(const bf16* __restrict__ qkv, const bf16* __restrict__ Vt,
                 bf16* __restrict__ out) {
  __shared__ __align__(16) bf16 smem[40960];  // 80 KB
  bf16* Qs = smem;             // [256 rows][64] swizzled, 32 KB
  bf16* Ks = smem + 16384;     // 3 x [64][64]  24 KB
  bf16* Vs = smem + 28672;     // 3 x [64][64]  24 KB (rows=d, cols=perm kv)
  const int tid = threadIdx.x, wave = tid >> 6, lane = tid & 63;
  const int l16 = lane & 15, lq = lane >> 4;
  const int id = blockIdx.y * 8 + blockIdx.x;
  const int w = (id & 7) * 64 + (id >> 3);
  const int qblk = w & 7, bh = w >> 3;
  const int b = bh >> 4, h = bh & 15;
  const int q0 = qblk * 256;
  const size_t rowbase = (size_t)b * 2048;
  const bf16* Qg = qkv + (rowbase + q0) * 3072 + h * 64;
  const bf16* Kg = qkv + rowbase * 3072 + 1024 + h * 64;
  const bf16* Vg = Vt + (size_t)bh * 64 * 2048;

  // prologue: stage Q (8 loads), then KV tiles 0,1 (4+4 loads)
#pragma unroll
  for (int i = 0; i < 8; i++) {
    const int c = i * 256 + wave * 64;
    const int cl = c + lane;
    const int r = cl >> 3, seg = cl & 7;
    gload_lds16(Qg + (size_t)r * 3072 + (seg ^ (r & 7)) * 8, (char*)Qs + c * 16);
  }
  auto stageKV = [&](int kt, int buf) {
    const int kv0 = kt * 64;
#pragma unroll
    for (int i = 0; i < 2; i++) {
      const int c = i * 256 + wave * 64;
      const int cl = c + lane;
      const int r = cl >> 3, seg = cl & 7;
      gload_lds16(Kg + (size_t)(kv0 + r) * 3072 + (seg ^ (r & 7)) * 8,
                  (char*)Ks + buf * 8192 + c * 16);
      gload_lds16(Vg + (size_t)r * 2048 + kv0 + (seg ^ (r & 7)) * 8,
                  (char*)Vs + buf * 8192 + c * 16);
    }
  };
  stageKV(0, 0);
  stageKV(1, 1);

  // Q resident after own vmcnt(8) + barrier (KV0/KV1 remain in flight)
  asm volatile("s_waitcnt vmcnt(8)" ::: "memory");
  __builtin_amdgcn_s_barrier();
  bf16x8 qb[4][2];
#pragma unroll
  for (int g = 0; g < 4; g++)
#pragma unroll
    for (int H = 0; H < 2; H++) {
      const int row = wave * 64 + g * 16 + l16;
      const int col = (H * 64 + lq * 16) ^ ((row & 7) << 4);
      qb[g][H] = *(const bf16x8*)((const char*)Qs + row * 128 + col);
    }

  f32x4 oacc[4][4] = {};
  f32x4 lacc[4] = {};
  bf16x8 onesb;
#pragma unroll
  for (int j = 0; j < 8; j++) onesb[j] = (bf16)1.0f;

  for (int t = 0; t < 32; t++) {
    if (t < 31) asm volatile("s_waitcnt vmcnt(4)" ::: "memory");
    else        asm volatile("s_waitcnt vmcnt(0)" ::: "memory");
    __builtin_amdgcn_s_barrier();
    __builtin_amdgcn_sched_barrier(0);
    if (t + 2 < 32) stageKV(t + 2, (t + 2) % 3);
    const char* Kb = (const char*)Ks + (t % 3) * 8192;
    const char* Vb = (const char*)Vs + (t % 3) * 8192;

    bf16x8 ka[2][4];
#pragma unroll
    for (int H = 0; H < 2; H++)
#pragma unroll
      for (int m = 0; m < 4; m++) {
        const int row = m * 16 + l16;
        const int col = (H * 64 + lq * 16) ^ ((row & 7) << 4);
        ka[H][m] = *(const bf16x8*)(Kb + row * 128 + col);
      }
    bf16x8 vb[2][4];
#pragma unroll
    for (int H = 0; H < 2; H++)
#pragma unroll
      for (int nd = 0; nd < 4; nd++) {
        const int row = nd * 16 + l16;
        const int col = (H * 64 + lq * 16) ^ ((row & 7) << 4);
        vb[H][nd] = *(const bf16x8*)(Vb + row * 128 + col);
      }
#pragma unroll
    for (int g = 0; g < 4; g++) {
      f32x4 sc[4];
      __builtin_amdgcn_s_setprio(1);
#pragma unroll
      for (int m = 0; m < 4; m++) {
        f32x4 z = {};
        sc[m] = __builtin_amdgcn_mfma_f32_16x16x32_bf16(ka[0][m], qb[g][0], z, 0, 0, 0);
        sc[m] = __builtin_amdgcn_mfma_f32_16x16x32_bf16(ka[1][m], qb[g][1], sc[m], 0, 0, 0);
      }
      __builtin_amdgcn_s_setprio(0);
      bf16x8 pa0, pa1;
#pragma unroll
      for (int m = 0; m < 2; m++)
#pragma unroll
        for (int r = 0; r < 4; r++)
          pa0[m * 4 + r] = (bf16)__builtin_amdgcn_exp2f(sc[m][r]);
#pragma unroll
      for (int m = 0; m < 2; m++)
#pragma unroll
        for (int r = 0; r < 4; r++)
          pa1[m * 4 + r] = (bf16)__builtin_amdgcn_exp2f(sc[2 + m][r]);
      __builtin_amdgcn_s_setprio(1);
#pragma unroll
      for (int nd = 0; nd < 4; nd++) {
        oacc[g][nd] = __builtin_amdgcn_mfma_f32_16x16x32_bf16(pa0, vb[0][nd], oacc[g][nd], 0, 0, 0);
        oacc[g][nd] = __builtin_amdgcn_mfma_f32_16x16x32_bf16(pa1, vb[1][nd], oacc[g][nd], 0, 0, 0);
      }
      lacc[g] = __builtin_amdgcn_mfma_f32_16x16x32_bf16(pa0, onesb, lacc[g], 0, 0, 0);
      lacc[g] = __builtin_amdgcn_mfma_f32_16x16x32_bf16(pa1, onesb, lacc[g], 0, 0, 0);
      __builtin_amdgcn_s_setprio(0);
    }
  }
#pragma unroll
  for (int g = 0; g < 4; g++) {
#pragma unroll
    for (int r = 0; r < 4; r++) {
      const float inv = 1.0f / lacc[g][r];
      const size_t row = rowbase + q0 + wave * 64 + g * 16 + lq * 4 + r;
#pragma unroll
      for (int nd = 0; nd < 4; nd++)
        out[row * 1024 + h * 64 + nd * 16 + l16] = (bf16)(oacc[g][nd][r] * inv);
    }
  }
}

// ---------------------------------------------------------------------------
extern "C" void kernel_launch(void* const* d_in, const int* in_sizes, int n_in,
                              void* d_out, int out_size, void* d_ws, size_t ws_size,
                              hipStream_t stream) {
  const float* x      = (const float*)d_in[0];
  const float* wq     = (const float*)d_in[1];
  const float* bq     = (const float*)d_in[2];
  const float* wk     = (const float*)d_in[3];
  const float* bk     = (const float*)d_in[4];
  const float* wv     = (const float*)d_in[5];
  const float* bv     = (const float*)d_in[6];
  const float* wo     = (const float*)d_in[7];
  const float* bo     = (const float*)d_in[8];
  const float* w1     = (const float*)d_in[9];
  const float* b1     = (const float*)d_in[10];
  const float* w2     = (const float*)d_in[11];
  const float* b2     = (const float*)d_in[12];
  const float* alpha1 = (const float*)d_in[13];
  const float* bias1  = (const float*)d_in[14];
  const float* alpha2 = (const float*)d_in[15];
  const float* bias2  = (const float*)d_in[16];
  float* out = (float*)d_out;  // h lives here, then final output

  const size_t MB = 1024ull * 1024ull;
  char* ws = (char*)d_ws;
  bf16*  wqkvT = (bf16*)(ws);                 // [3072][1024]   6 MB
  bf16*  woT   = (bf16*)(ws + 6 * MB);        // [1024][1024]   2 MB
  bf16*  w1T   = (bf16*)(ws + 8 * MB);        // [4096][1024]   8 MB
  bf16*  w2T   = (bf16*)(ws + 16 * MB);       // [1024][4096]   8 MB
  float* bqkv  = (float*)(ws + 24 * MB);      // [3072]
  bf16*  Z     = (bf16*)(ws + 24 * MB + 65536);   // [8192][1024] 16 MB (z1, Vt, z2, part1)
  bf16*  Vtb   = Z;
  bf16*  QKV   = (bf16*)(ws + 40 * MB + 65536);   // [8192][3072] 48 MB
  bf16*  AO    = (bf16*)(ws + 88 * MB + 65536);   // [8192][1024] 16 MB
  bf16*  FFN1  = QKV;  // [8192][4096] 64 MB, overlays dead QKV+AO region
  bf16*  PART  = (bf16*)ws;  // split-K partial 0 over dead weight transposes
  const size_t PART1_OFF = (24 * MB + 65536) / 2;  // partial 1 -> Z region (elems)

  const dim3 tb(32, 8);
  transpose_cvt4<<<dim3(32, 32, 4), tb, 0, stream>>>(wq, wk, wv, wo, wqkvT, woT);
  transpose_cvt<<<dim3(128, 32), tb, 0, stream>>>(w1, w1T, 1024, 4096);
  transpose_cvt<<<dim3(32, 128), tb, 0, stream>>>(w2, w2T, 4096, 1024);
  concat_bias<<<12, 256, 0, stream>>>(bq, bk, bv, bqkv);

  // LN1 -> z1
  ln_kernel<<<8192, 256, 0, stream>>>(x, Z, alpha1, bias1);
  // QKV = z1 @ [wq|wk|wv] + [bq|bk|bv]   (Q pre-scaled)
  gemm_v4<bf16, false, true><<<dim3(32, 12), 512, 0, stream>>>(
      Z, wqkvT, bqkv, QKV, 1024, 1024, 3072, 1024, 0, 0, 0);
  // V^T with PV k-perm (overlays dead z1)
  vt_prep<<<dim3(32, 64), 256, 0, stream>>>(QKV, Vtb);
  // attention -> AO
  attn_kernel<<<dim3(8, 64), 256, 0, stream>>>(QKV, Vtb, AO);
  // h = x + AO @ wo + bo   (h in d_out)
  gemm_bt<float, false, true><<<dim3(64, 8), 256, 0, stream>>>(
      AO, woT, bo, x, out, 8192, 1024, 1024);
  // LN2 -> z2
  ln_kernel<<<8192, 256, 0, stream>>>(out, Z, alpha2, bias2);
  // ffn1 = relu(z2 @ w1 + b1)
  gemm_v4<bf16, true, true><<<dim3(32, 16), 512, 0, stream>>>(
      Z, w1T, b1, FFN1, 1024, 1024, 4096, 1024, 0, 0, 0);
  // ffn2 partials: part[z] = FFN1[:, z*2048:] @ w2T[:, z*2048:]^T  (split-K)
  gemm_v4<bf16, false, false><<<dim3(32, 4, 2), 512, 0, stream>>>(
      FFN1, w2T, nullptr, PART, 4096, 4096, 1024, 2048, 2048, 2048, PART1_OFF);
  // out = h + part0 + part1 + b2
  ffn2_reduce<<<8192, 256, 0, stream>>>(PART, PART + PART1_OFF, b2, out);
}

// Round 7
// 349.717 us; speedup vs baseline: 1.8538x; 1.0065x over previous
//
#include <hip/hip_runtime.h>
#include <hip/hip_bf16.h>
#include <cstdint>
#include <cstddef>

typedef __bf16 bf16;
typedef __bf16 bf16x4 __attribute__((ext_vector_type(4)));
typedef __bf16 bf16x8 __attribute__((ext_vector_type(8)));
typedef float f32x4 __attribute__((ext_vector_type(4)));

// log2(e) / sqrt(64): folded into wq/bq so attn scores feed exp2 directly.
#define QK_SCALE 0.1803368801111204f

#define AS1 __attribute__((address_space(1)))
#define AS3 __attribute__((address_space(3)))

__device__ __forceinline__ void gload_lds16(const void* g, void* l) {
  __builtin_amdgcn_global_load_lds((AS1 void*)g, (AS3 void*)l, 16, 0, 0);
}

__device__ __forceinline__ float b2f(unsigned short u) {
  union { unsigned int i; float f; } v; v.i = (unsigned int)u << 16; return v.f;
}

// ---------------------------------------------------------------------------
// Transpose + fp32->bf16 convert: out[n][k] = (bf16) in[k][n].  in is [K][N].
__global__ __launch_bounds__(256)
void transpose_cvt(const float* __restrict__ in, bf16* __restrict__ out,
                   int K, int N) {
  __shared__ float t[32][33];
  const int tx = threadIdx.x, ty = threadIdx.y;
  const int n0 = blockIdx.x * 32, k0 = blockIdx.y * 32;
#pragma unroll
  for (int j = ty; j < 32; j += 8)
    t[j][tx] = in[(size_t)(k0 + j) * N + n0 + tx];
  __syncthreads();
#pragma unroll
  for (int j = ty; j < 32; j += 8)
    out[(size_t)(n0 + j) * K + k0 + tx] = (bf16)t[tx][j];
}

// Batched 1024x1024 transpose for wq/wk/wv/wo; wq gets QK_SCALE folded in.
__global__ __launch_bounds__(256)
void transpose_cvt4(const float* __restrict__ wq, const float* __restrict__ wk,
                    const float* __restrict__ wv, const float* __restrict__ wo,
                    bf16* __restrict__ wqkvT, bf16* __restrict__ woT) {
  __shared__ float t[32][33];
  const int tx = threadIdx.x, ty = threadIdx.y, z = blockIdx.z;
  const float* in = (z == 0) ? wq : (z == 1) ? wk : (z == 2) ? wv : wo;
  bf16* out = (z < 3) ? wqkvT + (size_t)z * 1024 * 1024 : woT;
  const float sc = (z == 0) ? QK_SCALE : 1.0f;
  const int n0 = blockIdx.x * 32, k0 = blockIdx.y * 32;
#pragma unroll
  for (int j = ty; j < 32; j += 8)
    t[j][tx] = in[(size_t)(k0 + j) * 1024 + n0 + tx] * sc;
  __syncthreads();
#pragma unroll
  for (int j = ty; j < 32; j += 8)
    out[(size_t)(n0 + j) * 1024 + k0 + tx] = (bf16)t[tx][j];
}

// ---------------------------------------------------------------------------
__global__ __launch_bounds__(256)
void concat_bias(const float* __restrict__ bq, const float* __restrict__ bk,
                 const float* __restrict__ bv, float* __restrict__ o) {
  int i = blockIdx.x * 256 + threadIdx.x;
  if (i < 1024) o[i] = bq[i] * QK_SCALE;
  else if (i < 2048) o[i] = bk[i - 1024];
  else o[i] = bv[i - 2048];
}

// ---------------------------------------------------------------------------
// LayerNorm (torch semantics: ddof=1, eps on std), fp32 in -> bf16 out.
__global__ __launch_bounds__(256)
void ln_kernel(const float* __restrict__ x, bf16* __restrict__ y,
               const float* __restrict__ alpha_p, const float* __restrict__ beta_p) {
  const int row = blockIdx.x;
  const float4 v = ((const float4*)(x + (size_t)row * 1024))[threadIdx.x];
  float s = v.x + v.y + v.z + v.w;
  float ss = v.x * v.x + v.y * v.y + v.z * v.z + v.w * v.w;
#pragma unroll
  for (int m = 1; m < 64; m <<= 1) {
    s += __shfl_xor(s, m);
    ss += __shfl_xor(ss, m);
  }
  __shared__ float red[8];
  const int wave = threadIdx.x >> 6, lane = threadIdx.x & 63;
  if (lane == 0) { red[wave] = s; red[4 + wave] = ss; }
  __syncthreads();
  s = red[0] + red[1] + red[2] + red[3];
  ss = red[4] + red[5] + red[6] + red[7];
  const float mean = s * (1.0f / 1024.0f);
  const float var = fmaxf(ss - 1024.0f * mean * mean, 0.0f) * (1.0f / 1023.0f);
  const float k = alpha_p[0] / (sqrtf(var) + 1e-6f);
  const float beta = beta_p[0];
  union { bf16 b[4]; uint2 u; } pk;
  pk.b[0] = (bf16)((v.x - mean) * k + beta);
  pk.b[1] = (bf16)((v.y - mean) * k + beta);
  pk.b[2] = (bf16)((v.z - mean) * k + beta);
  pk.b[3] = (bf16)((v.w - mean) * k + beta);
  ((uint2*)(y + (size_t)row * 1024))[threadIdx.x] = pk.u;
}

// ---------------------------------------------------------------------------
// GEMM v3 (128x128, 2-phase) kept for WO (memory-floor-bound, small FLOP).
template <typename OutT, bool RELU, bool RESID>
__global__ __launch_bounds__(256)
void gemm_bt(const bf16* __restrict__ A, const bf16* __restrict__ Bt,
             const float* __restrict__ bias, const float* __restrict__ resid,
             OutT* __restrict__ C, int M, int N, int K) {
  __shared__ __align__(16) bf16 As[2][128 * 32];
  __shared__ __align__(16) bf16 Bs[2][128 * 32];
  const int tid = threadIdx.x;
  const int wave = tid >> 6, lane = tid & 63;
  const int l16 = lane & 15, lq = lane >> 4;
  const int nwg = gridDim.x * gridDim.y;
  const int id = blockIdx.y * gridDim.x + blockIdx.x;
  const int w = (id & 7) * (nwg >> 3) + (id >> 3);
  const int bm = (w / gridDim.y) * 128, bn = (w % gridDim.y) * 128;
  const int wr = wave >> 1, wc = wave & 1;

  const int tmp = (lane * 16) ^ (((lane >> 3) & 7) << 4);
  const int srow = tmp >> 6, sseg = (tmp >> 4) & 3;
  const bf16* Ab = A + (size_t)bm * K + sseg * 8;
  const bf16* Bb = Bt + (size_t)bn * K + sseg * 8;

  auto STAGE = [&](int k0, int buf) {
#pragma unroll
    for (int i = 0; i < 2; i++) {
      const int chunk = wave * 2 + i;
      const int r = chunk * 16 + srow;
      gload_lds16(Ab + (size_t)r * K + k0, (char*)As[buf] + chunk * 1024);
      gload_lds16(Bb + (size_t)r * K + k0, (char*)Bs[buf] + chunk * 1024);
    }
  };
  auto swz = [&](int row) -> int {
    return (row >> 1) * 128 + (((((row & 1) << 2) | lq) ^ ((row >> 1) & 7)) << 4);
  };

  STAGE(0, 0);
  __syncthreads();

  f32x4 acc[4][4] = {};
  const int nk = K >> 5;
  for (int t = 0; t < nk; t++) {
    const int cur = t & 1;
    if (t + 1 < nk) STAGE((t + 1) << 5, cur ^ 1);
    bf16x8 a[4], b[4];
#pragma unroll
    for (int m = 0; m < 4; m++)
      a[m] = *(const bf16x8*)((const char*)As[cur] + swz(wr * 64 + m * 16 + l16));
#pragma unroll
    for (int n = 0; n < 4; n++)
      b[n] = *(const bf16x8*)((const char*)Bs[cur] + swz(wc * 64 + n * 16 + l16));
#pragma unroll
    for (int m = 0; m < 4; m++)
#pragma unroll
      for (int n = 0; n < 4; n++)
        acc[m][n] = __builtin_amdgcn_mfma_f32_16x16x32_bf16(a[m], b[n], acc[m][n], 0, 0, 0);
    __syncthreads();
  }
#pragma unroll
  for (int m = 0; m < 4; m++) {
    const int row0 = bm + wr * 64 + m * 16 + lq * 4;
#pragma unroll
    for (int n = 0; n < 4; n++) {
      const int col = bn + wc * 64 + n * 16 + l16;
      const float bv = bias[col];
#pragma unroll
      for (int j = 0; j < 4; j++) {
        float v = acc[m][n][j] + bv;
        if (RELU) v = fmaxf(v, 0.0f);
        if (RESID) v += resid[(size_t)(row0 + j) * N + col];
        C[(size_t)(row0 + j) * N + col] = (OutT)v;
      }
    }
  }
}

// ---------------------------------------------------------------------------
// GEMM v5: 256x256 tile, BK=32, 8 waves, FOUR-buffer LDS rotation with
// prefetch distance 3 and counted vmcnt(8) (2 tiles stay in flight across the
// tile-boundary wait -> HBM latency ~900cy fully covered by ~3 iters of MFMA).
// One barrier per tile, setprio'd MFMA clusters, zero-conflict XOR swizzle,
// XCD-chunked grid.  1 block/CU (128 KB LDS).
template <typename OutT, bool RELU, bool BIAS>
__global__ __launch_bounds__(512, 2)
void gemm_v4(const bf16* __restrict__ A, const bf16* __restrict__ Bt,
             const float* __restrict__ bias, OutT* __restrict__ C,
             int lda, int ldb, int ldc, int K,
             int azs, int bzs, size_t czs) {
  __shared__ __align__(16) char lds[4 * 32768];  // 128 KB
  const int tid = threadIdx.x;
  const int wave = tid >> 6, lane = tid & 63;
  const int l16 = lane & 15, lq = lane >> 4;
  const int wr = wave >> 2, wc = wave & 3;
  const int nwg = gridDim.x * gridDim.y;
  const int id = blockIdx.y * gridDim.x + blockIdx.x;
  const int w = (id & 7) * (nwg >> 3) + (id >> 3);
  const int bm = (w / gridDim.y) * 256, bn = (w % gridDim.y) * 256;

  A  += (size_t)blockIdx.z * azs;
  Bt += (size_t)blockIdx.z * bzs;
  C  += (size_t)blockIdx.z * czs;

  const int p = lane >> 3, jj = (lane & 7) ^ p;
  const int lrow = p * 2 + (jj >> 2), lseg = jj & 3;
  const bf16* Abase = A + (size_t)bm * lda + lseg * 8;
  const bf16* Bbase = Bt + (size_t)bn * ldb + lseg * 8;

  auto STAGEQ = [&](int t, int qq) {  // qq: 0,1 = A halves; 2,3 = B halves
    const int k0 = t << 5;
    const int grow = (qq & 1) * 128 + wave * 16 + lrow;
    const void* src = (qq < 2) ? (const void*)(Abase + (size_t)grow * lda + k0)
                               : (const void*)(Bbase + (size_t)grow * ldb + k0);
    gload_lds16(src, lds + (t & 3) * 32768 + qq * 8192 + wave * 1024);
  };
  auto swz = [&](int row) -> int {
    return (row >> 1) * 128 + (((((row & 1) << 2) | lq) ^ ((row >> 1) & 7)) << 4);
  };

  const int nk = K >> 5;
  // prologue: stage tiles 0,1,2 (12 loads/wave in flight)
#pragma unroll
  for (int tt = 0; tt < 3; tt++)
#pragma unroll
    for (int qq = 0; qq < 4; qq++) STAGEQ(tt, qq);

  f32x4 acc[8][4] = {};
  for (int t = 0; t < nk; t++) {
    const char* buf = lds + (t & 3) * 32768;
    // own 4 loads of tile t done; tiles t+1,t+2 (8 loads) stay in flight.
    if (t + 2 < nk)      asm volatile("s_waitcnt vmcnt(8)" ::: "memory");
    else if (t + 1 < nk) asm volatile("s_waitcnt vmcnt(4)" ::: "memory");
    else                 asm volatile("s_waitcnt vmcnt(0)" ::: "memory");
    __builtin_amdgcn_s_barrier();  // cross-wave RAW + WAR(buf (t+3)&3) closed
    __builtin_amdgcn_sched_barrier(0);
    if (t + 3 < nk) { STAGEQ(t + 3, 0); STAGEQ(t + 3, 1); }
    bf16x8 a0[4], b0[4], a1[4];
#pragma unroll
    for (int i = 0; i < 4; i++)
      a0[i] = *(const bf16x8*)(buf + swz(wr * 128 + i * 16 + l16));
#pragma unroll
    for (int n = 0; n < 4; n++)
      b0[n] = *(const bf16x8*)(buf + 16384 + swz(wc * 64 + n * 16 + l16));
    if (t + 3 < nk) { STAGEQ(t + 3, 2); STAGEQ(t + 3, 3); }
#pragma unroll
    for (int i = 0; i < 4; i++)
      a1[i] = *(const bf16x8*)(buf + swz(wr * 128 + 64 + i * 16 + l16));
    __builtin_amdgcn_sched_barrier(0);
    __builtin_amdgcn_s_setprio(1);
#pragma unroll
    for (int i = 0; i < 4; i++)
#pragma unroll
      for (int n = 0; n < 4; n++)
        acc[i][n] = __builtin_amdgcn_mfma_f32_16x16x32_bf16(a0[i], b0[n], acc[i][n], 0, 0, 0);
    __builtin_amdgcn_s_setprio(0);
    __builtin_amdgcn_sched_barrier(0);
    __builtin_amdgcn_s_setprio(1);
#pragma unroll
    for (int i = 0; i < 4; i++)
#pragma unroll
      for (int n = 0; n < 4; n++)
        acc[4 + i][n] = __builtin_amdgcn_mfma_f32_16x16x32_bf16(a1[i], b0[n], acc[4 + i][n], 0, 0, 0);
    __builtin_amdgcn_s_setprio(0);
  }
#pragma unroll
  for (int m = 0; m < 8; m++) {
    const int row0 = bm + wr * 128 + m * 16 + lq * 4;
#pragma unroll
    for (int n = 0; n < 4; n++) {
      const int col = bn + wc * 64 + n * 16 + l16;
      const float bv = BIAS ? bias[col] : 0.0f;
#pragma unroll
      for (int j = 0; j < 4; j++) {
        float v = acc[m][n][j] + bv;
        if (RELU) v = fmaxf(v, 0.0f);
        C[(size_t)(row0 + j) * ldc + col] = (OutT)v;
      }
    }
  }
}

// ---------------------------------------------------------------------------
// FFN2 split-K reduce: out = out(h) + p0 + p1 + b2   over [8192][1024]
__global__ __launch_bounds__(256)
void ffn2_reduce(const bf16* __restrict__ p0, const bf16* __restrict__ p1,
                 const float* __restrict__ b2, float* __restrict__ out) {
  const size_t i = (size_t)blockIdx.x * 256 + threadIdx.x;
  float4 h = ((const float4*)out)[i];
  const ushort4 a = ((const ushort4*)p0)[i];
  const ushort4 b = ((const ushort4*)p1)[i];
  const float4 bb = ((const float4*)b2)[i & 255];
  h.x += b2f(a.x) + b2f(b.x) + bb.x;
  h.y += b2f(a.y) + b2f(b.y) + bb.y;
  h.z += b2f(a.z) + b2f(b.z) + bb.z;
  h.w += b2f(a.w) + b2f(b.w) + bb.w;
  ((float4*)out)[i] = h;
}

// ---------------------------------------------------------------------------
// V^T prep with PV k-permutation baked in:
//   stored position p (bits [H][lq1 lq0][j2 j1 j0]) holds kv = [H][j2][lq][j1 j0]
__global__ __launch_bounds__(256)
void vt_prep(const bf16* __restrict__ qkv, bf16* __restrict__ Vt) {
  __shared__ __align__(16) bf16 Vl[64 * 64];
  const int tid = threadIdx.x;
  const int sblk = blockIdx.x, bh = blockIdx.y, b = bh >> 4, h = bh & 15;
  const size_t srow = (size_t)b * 2048 + sblk * 64;
  const bf16* src = qkv + srow * 3072 + 2048 + h * 64;
#pragma unroll
  for (int i = 0; i < 2; i++) {
    int c = i * 256 + tid;
    int s = c >> 3, dseg = c & 7;
    int col = dseg ^ (s & 7) ^ (s >> 3);
    *(uint4*)((char*)Vl + s * 128 + col * 16) =
        *(const uint4*)(src + (size_t)s * 3072 + dseg * 8);
  }
  __syncthreads();
  bf16* dst = Vt + (size_t)bh * 64 * 2048 + sblk * 64;
#pragma unroll
  for (int i = 0; i < 2; i++) {
    int c = i * 256 + tid;
    int d = c >> 3, grp = c & 7;
    union { bf16 v[8]; uint4 u; } pk;
#pragma unroll
    for (int j = 0; j < 8; j++) {
      int pp = grp * 8 + j;  // stored position within 64-kv tile
      int s = (pp & 32) | (((pp >> 2) & 1) << 4) | (((pp >> 3) & 3) << 2) | (pp & 3);
      int col = (d >> 3) ^ (s & 7) ^ (s >> 3);
      pk.v[j] = *(const bf16*)((char*)Vl + s * 128 + col * 16 + ((2 * d) & 15));
    }
    *(uint4*)(dst + (size_t)d * 2048 + grp * 8) = pk.u;
  }
}

// ---------------------------------------------------------------------------
// Flash attention v3.1: Q pre-scaled by log2e/sqrt(dk) (exp2 direct), Q-frags
// hoisted to prologue (counted vmcnt), 3-buffer KV rotation, one barrier/tile,
// V-perm single-b128 PV fragments, setprio'd MFMA, fixed-max softmax, L=ones-MFMA.
__global__ __launch_bounds__(256, 2)
void attn_kernel(const bf16* __restrict__ qkv, const bf16* __restrict__ Vt,
                 bf16* __restrict__ out) {
  __shared__ __align__(16) bf16 smem[40960];  // 80 KB
  bf16* Qs = smem;             // [256 rows][64] swizzled, 32 KB
  bf16* Ks = smem + 16384;     // 3 x [64][64]  24 KB
  bf16* Vs = smem + 28672;     // 3 x [64][64]  24 KB (rows=d, cols=perm kv)
  const int tid = threadIdx.x, wave = tid >> 6, lane = tid & 63;
  const int l16 = lane & 15, lq = lane >> 4;
  const int id = blockIdx.y * 8 + blockIdx.x;
  const int w = (id & 7) * 64 + (id >> 3);
  const int qblk = w & 7, bh = w >> 3;
  const int b = bh >> 4, h = bh & 15;
  const int q0 = qblk * 256;
  const size_t rowbase = (size_t)b * 2048;
  const bf16* Qg = qkv + (rowbase + q0) * 3072 + h * 64;
  const bf16* Kg = qkv + rowbase * 3072 + 1024 + h * 64;
  const bf16* Vg = Vt + (size_t)bh * 64 * 2048;

  // prologue: stage Q (8 loads), then KV tiles 0,1 (4+4 loads)
#pragma unroll
  for (int i = 0; i < 8; i++) {
    const int c = i * 256 + wave * 64;
    const int cl = c + lane;
    const int r = cl >> 3, seg = cl & 7;
    gload_lds16(Qg + (size_t)r * 3072 + (seg ^ (r & 7)) * 8, (char*)Qs + c * 16);
  }
  auto stageKV = [&](int kt, int buf) {
    const int kv0 = kt * 64;
#pragma unroll
    for (int i = 0; i < 2; i++) {
      const int c = i * 256 + wave * 64;
      const int cl = c + lane;
      const int r = cl >> 3, seg = cl & 7;
      gload_lds16(Kg + (size_t)(kv0 + r) * 3072 + (seg ^ (r & 7)) * 8,
                  (char*)Ks + buf * 8192 + c * 16);
      gload_lds16(Vg + (size_t)r * 2048 + kv0 + (seg ^ (r & 7)) * 8,
                  (char*)Vs + buf * 8192 + c * 16);
    }
  };
  stageKV(0, 0);
  stageKV(1, 1);

  // Q resident after own vmcnt(8) + barrier (KV0/KV1 remain in flight)
  asm volatile("s_waitcnt vmcnt(8)" ::: "memory");
  __builtin_amdgcn_s_barrier();
  bf16x8 qb[4][2];
#pragma unroll
  for (int g = 0; g < 4; g++)
#pragma unroll
    for (int H = 0; H < 2; H++) {
      const int row = wave * 64 + g * 16 + l16;
      const int col = (H * 64 + lq * 16) ^ ((row & 7) << 4);
      qb[g][H] = *(const bf16x8*)((const char*)Qs + row * 128 + col);
    }

  f32x4 oacc[4][4] = {};
  f32x4 lacc[4] = {};
  bf16x8 onesb;
#pragma unroll
  for (int j = 0; j < 8; j++) onesb[j] = (bf16)1.0f;

  for (int t = 0; t < 32; t++) {
    if (t < 31) asm volatile("s_waitcnt vmcnt(4)" ::: "memory");
    else        asm volatile("s_waitcnt vmcnt(0)" ::: "memory");
    __builtin_amdgcn_s_barrier();
    __builtin_amdgcn_sched_barrier(0);
    if (t + 2 < 32) stageKV(t + 2, (t + 2) % 3);
    const char* Kb = (const char*)Ks + (t % 3) * 8192;
    const char* Vb = (const char*)Vs + (t % 3) * 8192;

    bf16x8 ka[2][4];
#pragma unroll
    for (int H = 0; H < 2; H++)
#pragma unroll
      for (int m = 0; m < 4; m++) {
        const int row = m * 16 + l16;
        const int col = (H * 64 + lq * 16) ^ ((row & 7) << 4);
        ka[H][m] = *(const bf16x8*)(Kb + row * 128 + col);
      }
    bf16x8 vb[2][4];
#pragma unroll
    for (int H = 0; H < 2; H++)
#pragma unroll
      for (int nd = 0; nd < 4; nd++) {
        const int row = nd * 16 + l16;
        const int col = (H * 64 + lq * 16) ^ ((row & 7) << 4);
        vb[H][nd] = *(const bf16x8*)(Vb + row * 128 + col);
      }
#pragma unroll
    for (int g = 0; g < 4; g++) {
      f32x4 sc[4];
      __builtin_amdgcn_s_setprio(1);
#pragma unroll
      for (int m = 0; m < 4; m++) {
        f32x4 z = {};
        sc[m] = __builtin_amdgcn_mfma_f32_16x16x32_bf16(ka[0][m], qb[g][0], z, 0, 0, 0);
        sc[m] = __builtin_amdgcn_mfma_f32_16x16x32_bf16(ka[1][m], qb[g][1], sc[m], 0, 0, 0);
      }
      __builtin_amdgcn_s_setprio(0);
      bf16x8 pa0, pa1;
#pragma unroll
      for (int m = 0; m < 2; m++)
#pragma unroll
        for (int r = 0; r < 4; r++)
          pa0[m * 4 + r] = (bf16)__builtin_amdgcn_exp2f(sc[m][r]);
#pragma unroll
      for (int m = 0; m < 2; m++)
#pragma unroll
        for (int r = 0; r < 4; r++)
          pa1[m * 4 + r] = (bf16)__builtin_amdgcn_exp2f(sc[2 + m][r]);
      __builtin_amdgcn_s_setprio(1);
#pragma unroll
      for (int nd = 0; nd < 4; nd++) {
        oacc[g][nd] = __builtin_amdgcn_mfma_f32_16x16x32_bf16(pa0, vb[0][nd], oacc[g][nd], 0, 0, 0);
        oacc[g][nd] = __builtin_amdgcn_mfma_f32_16x16x32_bf16(pa1, vb[1][nd], oacc[g][nd], 0, 0, 0);
      }
      lacc[g] = __builtin_amdgcn_mfma_f32_16x16x32_bf16(pa0, onesb, lacc[g], 0, 0, 0);
      lacc[g] = __builtin_amdgcn_mfma_f32_16x16x32_bf16(pa1, onesb, lacc[g], 0, 0, 0);
      __builtin_amdgcn_s_setprio(0);
    }
  }
#pragma unroll
  for (int g = 0; g < 4; g++) {
#pragma unroll
    for (int r = 0; r < 4; r++) {
      const float inv = 1.0f / lacc[g][r];
      const size_t row = rowbase + q0 + wave * 64 + g * 16 + lq * 4 + r;
#pragma unroll
      for (int nd = 0; nd < 4; nd++)
        out[row * 1024 + h * 64 + nd * 16 + l16] = (bf16)(oacc[g][nd][r] * inv);
    }
  }
}

// ---------------------------------------------------------------------------
extern "C" void kernel_launch(void* const* d_in, const int* in_sizes, int n_in,
                              void* d_out, int out_size, void* d_ws, size_t ws_size,
                              hipStream_t stream) {
  const float* x      = (const float*)d_in[0];
  const float* wq     = (const float*)d_in[1];
  const float* bq     = (const float*)d_in[2];
  const float* wk     = (const float*)d_in[3];
  const float* bk     = (const float*)d_in[4];
  const float* wv     = (const float*)d_in[5];
  const float* bv     = (const float*)d_in[6];
  const float* wo     = (const float*)d_in[7];
  const float* bo     = (const float*)d_in[8];
  const float* w1     = (const float*)d_in[9];
  const float* b1     = (const float*)d_in[10];
  const float* w2     = (const float*)d_in[11];
  const float* b2     = (const float*)d_in[12];
  const float* alpha1 = (const float*)d_in[13];
  const float* bias1  = (const float*)d_in[14];
  const float* alpha2 = (const float*)d_in[15];
  const float* bias2  = (const float*)d_in[16];
  float* out = (float*)d_out;  // h lives here, then final output

  const size_t MB = 1024ull * 1024ull;
  char* ws = (char*)d_ws;
  bf16*  wqkvT = (bf16*)(ws);                 // [3072][1024]   6 MB
  bf16*  woT   = (bf16*)(ws + 6 * MB);        // [1024][1024]   2 MB
  bf16*  w1T   = (bf16*)(ws + 8 * MB);        // [4096][1024]   8 MB
  bf16*  w2T   = (bf16*)(ws + 16 * MB);       // [1024][4096]   8 MB
  float* bqkv  = (float*)(ws + 24 * MB);      // [3072]
  bf16*  Z     = (bf16*)(ws + 24 * MB + 65536);   // [8192][1024] 16 MB (z1, Vt, z2, part1)
  bf16*  Vtb   = Z;
  bf16*  QKV   = (bf16*)(ws + 40 * MB + 65536);   // [8192][3072] 48 MB
  bf16*  AO    = (bf16*)(ws + 88 * MB + 65536);   // [8192][1024] 16 MB
  bf16*  FFN1  = QKV;  // [8192][4096] 64 MB, overlays dead QKV+AO region
  bf16*  PART  = (bf16*)ws;  // split-K partial 0 over dead weight transposes
  const size_t PART1_OFF = (24 * MB + 65536) / 2;  // partial 1 -> Z region (elems)

  const dim3 tb(32, 8);
  transpose_cvt4<<<dim3(32, 32, 4), tb, 0, stream>>>(wq, wk, wv, wo, wqkvT, woT);
  transpose_cvt<<<dim3(128, 32), tb, 0, stream>>>(w1, w1T, 1024, 4096);
  transpose_cvt<<<dim3(32, 128), tb, 0, stream>>>(w2, w2T, 4096, 1024);
  concat_bias<<<12, 256, 0, stream>>>(bq, bk, bv, bqkv);

  // LN1 -> z1
  ln_kernel<<<8192, 256, 0, stream>>>(x, Z, alpha1, bias1);
  // QKV = z1 @ [wq|wk|wv] + [bq|bk|bv]   (Q pre-scaled)
  gemm_v4<bf16, false, true><<<dim3(32, 12), 512, 0, stream>>>(
      Z, wqkvT, bqkv, QKV, 1024, 1024, 3072, 1024, 0, 0, 0);
  // V^T with PV k-perm (overlays dead z1)
  vt_prep<<<dim3(32, 64), 256, 0, stream>>>(QKV, Vtb);
  // attention -> AO
  attn_kernel<<<dim3(8, 64), 256, 0, stream>>>(QKV, Vtb, AO);
  // h = x + AO @ wo + bo   (h in d_out)
  gemm_bt<float, false, true><<<dim3(64, 8), 256, 0, stream>>>(
      AO, woT, bo, x, out, 8192, 1024, 1024);
  // LN2 -> z2
  ln_kernel<<<8192, 256, 0, stream>>>(out, Z, alpha2, bias2);
  // ffn1 = relu(z2 @ w1 + b1)
  gemm_v4<bf16, true, true><<<dim3(32, 16), 512, 0, stream>>>(
      Z, w1T, b1, FFN1, 1024, 1024, 4096, 1024, 0, 0, 0);
  // ffn2 partials: part[z] = FFN1[:, z*2048:] @ w2T[:, z*2048:]^T  (split-K)
  gemm_v4<bf16, false, false><<<dim3(32, 4, 2), 512, 0, stream>>>(
      FFN1, w2T, nullptr, PART, 4096, 4096, 1024, 2048, 2048, 2048, PART1_OFF);
  // out = h + part0 + part1 + b2
  ffn2_reduce<<<8192, 256, 0, stream>>>(PART, PART + PART1_OFF, b2, out);
}